// Round 9
// baseline (777.412 us; speedup 1.0000x reference)
//
#include <hip/hip_runtime.h>

#define NN 5000
#define EE 120000

typedef __bf16 bf16_t;
typedef __bf16 bf16x8 __attribute__((ext_vector_type(8)));
typedef float f32x4 __attribute__((ext_vector_type(4)));

// W^T offsets (elements) inside ws
#define OFF_EEW2T 0
#define OFF_ECW1T 65536
#define OFF_ECW2T 196608
#define OFF_FW1T  262144
#define OFF_FW2T  524288
#define OFF_LN1T  786432
#define OFF_LN2T  1048576
#define OFF_GW1T  1310720
#define OFF_GW2T  1441792

// ws byte offsets (total 72,069,120 B — proven available)
#define WSOFF_H16   2949120
#define WSOFF_HL    5509120
#define WSOFF_AGG   8069120
#define WSOFF_EATTR 10629120
// transient region inside AGG (free until k_msg runs)
#define AGGOFF_BFOLD 524288
#define AGGOFF_PERM  528384

// edge-class metadata (within-molecule): order [d1, d2, d3, d>=4]
__device__ __constant__ int C_CNT[4] = {48, 46, 44, 462};
__device__ __constant__ int C_OFF[4] = {0, 48, 94, 138};

// XOR-swizzled [rows x 256] bf16 tile: 16B chunks permuted by row, conflict-free
__device__ __forceinline__ int swz(int r, int c) {
  return r * 256 + ((((c >> 3) ^ (r & 7)) << 3) | (c & 7));
}

__device__ __forceinline__ float silu_f(float x) { return x / (1.f + __expf(-x)); }
// fast shifted-softplus: native v_exp/v_log; |x| is O(1) here
__device__ __forceinline__ float ssp_f(float x) {
  return __logf(1.f + __expf(x)) - 0.6931472f;
}

// async global->LDS 16B copy: LDS dest = uniform base + lane*16 (HW),
// global source is per-lane (pre-swizzled to match the swizzled read layout)
__device__ __forceinline__ void async16(bf16_t* lds, const bf16_t* g) {
  __builtin_amdgcn_global_load_lds(
      (__attribute__((address_space(1))) const void*)g,
      (__attribute__((address_space(3))) void*)lds, 16, 0, 0);
}

// dst-major storage index for edge e (eattr is stored permuted):
// e = m*600 + i*24 + q, j = q + (q>=i)  ->  p = m*600 + j*24 + (i>j ? i-1 : i)
__device__ __forceinline__ int eperm(int e) {
  int m = e / 600, eloc = e - m * 600;
  int i = eloc / 24, q = eloc - i * 24;
  int j = q + (q >= i);
  return m * 600 + j * 24 + i - (i > j);
}

__device__ __forceinline__ bf16x8 zero8() {
  bf16x8 v;
#pragma unroll
  for (int q = 0; q < 8; ++q) v[q] = (__bf16)0.f;
  return v;
}

template<int RT, int NT>
__device__ __forceinline__ void zacc(f32x4 (&acc)[RT][NT]) {
#pragma unroll
  for (int i = 0; i < RT; ++i)
#pragma unroll
    for (int j = 0; j < NT; ++j) {
      f32x4 z = {0.f, 0.f, 0.f, 0.f};
      acc[i][j] = z;
    }
}

// A: LDS swizzled tile, rows rt*16+l15, k chunks ks*32+quad*8
// WT: global W^T [N, ldK] row-major (bf16); effective B[k][n] = WT[n*ldK + k]
template<int RT, int NT, int KS>
__device__ __forceinline__ void gemm_lds(const bf16_t* __restrict__ A,
                                         const bf16_t* __restrict__ WT, int ldK,
                                         int colBase, f32x4 (&acc)[RT][NT], int lane) {
  const int l15 = lane & 15, quad = lane >> 4;
#pragma unroll
  for (int ks = 0; ks < KS; ++ks) {
    const int kc = ks * 4 + quad;
    bf16x8 a[RT];
#pragma unroll
    for (int rt = 0; rt < RT; ++rt) {
      int r = rt * 16 + l15;
      a[rt] = *(const bf16x8*)(A + r * 256 + ((kc ^ (r & 7)) << 3));
    }
#pragma unroll
    for (int nt = 0; nt < NT; ++nt) {
      const bf16x8 b = *(const bf16x8*)(WT + (size_t)(colBase + nt * 16 + l15) * ldK + kc * 8);
#pragma unroll
      for (int rt = 0; rt < RT; ++rt)
        acc[rt][nt] = __builtin_amdgcn_mfma_f32_16x16x32_bf16(a[rt], b, acc[rt][nt], 0, 0, 0);
    }
  }
}

// -------- fused setup: transpose ∪ fold ∪ foldb ∪ node ∪ prep ∪ out-copy --------
// grid partition (flat blockIdx.x, 256 threads):
//   [0,4992)            weight transpose (1,277,952 elems)
//   [4992,6016)         k_fold (p = b>>8, k = b&255)
//   [6016,6020)         k_foldb (p = b)
//   [6020,8520)         node embedding (2 nodes / block)
//   [8520,8521)         perm builder
//   [8521,9459)         out[EE..3EE] = float(ei)  (240,000 elems)
// Every body is arithmetically identical to the former standalone kernel.
__global__ __launch_bounds__(256) void k_setup(
    const float* eeW2, const float* ecW1, const float* ecW2,
    const float* fW1, const float* fW2, const float* ln1, const float* ln2,
    const float* gW1, const float* gW2, bf16_t* WT,
    const float* bemb, const float* eeb2, const float* ecb1,
    bf16_t* wfoldT, float* bfold, int* perm,
    const float* r_feat, const float* p_feat, const float* emb, const float* Wf,
    const int* atype, bf16_t* h16, const int* ei, float* out) {
  __shared__ float rf[2][27], pf[2][27];
  const int tid = threadIdx.x;
  int b = blockIdx.x;
  if (b < 4992) {                       // ---- weight transpose ----
    int g = b * 256 + tid;
    if (g < 1114112) {                  // segs 0..16: K=256, Nn=256
      int seg = g >> 16, idx = g & 65535;
      const float* src; int off;
      if (seg == 0)       { src = ecW2;                    off = OFF_ECW2T; }
      else if (seg <= 4)  { src = fW1 + (seg - 1) * 65536; off = OFF_FW1T + (seg - 1) * 65536; }
      else if (seg <= 8)  { src = fW2 + (seg - 5) * 65536; off = OFF_FW2T + (seg - 5) * 65536; }
      else if (seg <= 12) { src = ln1 + (seg - 9) * 65536; off = OFF_LN1T + (seg - 9) * 65536; }
      else                { src = ln2 + (seg - 13) * 65536; off = OFF_LN2T + (seg - 13) * 65536; }
      int k = idx & 255, n = idx >> 8;
      WT[off + idx] = (bf16_t)src[k * 256 + n];
    } else if (g < 1245184) {           // seg 17: gW1, K=512, Nn=256
      int idx = g - 1114112;
      int k = idx & 511, n = idx >> 9;
      WT[OFF_GW1T + idx] = (bf16_t)gW1[k * 256 + n];
    } else if (g < 1277952) {           // seg 18: gW2, K=256, Nn=128
      int idx = g - 1245184;
      int k = idx & 255, n = idx >> 8;
      WT[OFF_GW2T + idx] = (bf16_t)gW2[k * 128 + n];
    }
    return;
  }
  b -= 4992;
  if (b < 1024) {                       // ---- k_fold ----
    const int p = b >> 8, k = b & 255, n = tid;
    const int TR[4] = {1, 2, 3, 0}, TP[4] = {3, 2, 1, 0};
    const float* br = bemb + TR[p] * 256;
    const float* bp = bemb + TP[p] * 256;
    float acc = 0.f;
    for (int m = 0; m < 256; ++m) {
      float wc = br[m] * ecW1[m * 256 + n] + bp[m] * ecW1[(256 + m) * 256 + n];
      acc += eeW2[k * 256 + m] * wc;
    }
    wfoldT[p * 65536 + n * 256 + k] = (bf16_t)acc;
    return;
  }
  b -= 1024;
  if (b < 4) {                          // ---- k_foldb ----
    const int p = b, n = tid;
    const int TR[4] = {1, 2, 3, 0}, TP[4] = {3, 2, 1, 0};
    const float* br = bemb + TR[p] * 256;
    const float* bp = bemb + TP[p] * 256;
    float acc = ecb1[n];
    for (int m = 0; m < 256; ++m) {
      float wc = br[m] * ecW1[m * 256 + n] + bp[m] * ecW1[(256 + m) * 256 + n];
      acc += eeb2[m] * wc;
    }
    bfold[p * 256 + n] = acc;
    return;
  }
  b -= 4;
  if (b < 2500) {                       // ---- node embedding, 2 nodes/block ----
    int half = tid >> 7, t = tid & 127;
    int n = b * 2 + half;
    if (t < 27) { rf[half][t] = r_feat[n * 27 + t]; pf[half][t] = p_feat[n * 27 + t]; }
    __syncthreads();
    float fr = 0.f, fp = 0.f;
#pragma unroll
    for (int k = 0; k < 27; ++k) {
      float w = Wf[k * 128 + t];
      fr += rf[half][k] * w; fp += pf[half][k] * w;
    }
    int at = atype[n];
    size_t base = (size_t)n * 256;
    h16[base + t] = (bf16_t)(emb[at * 128 + t] + fr);
    h16[base + 128 + t] = (bf16_t)(fp - fr);
    return;
  }
  b -= 2500;
  if (b < 1) {                          // ---- perm builder ----
    for (int e = tid; e < 600; e += 256) {
      int i = e / 24, q = e % 24;
      int j = q + (q >= i ? 1 : 0);
      int d = (i > j) ? (i - j) : (j - i);
      int cls = (d <= 3) ? (d - 1) : 3;
      int rank = 0;
      for (int e2 = 0; e2 < e; ++e2) {
        int i2 = e2 / 24, q2 = e2 % 24;
        int j2 = q2 + (q2 >= i2 ? 1 : 0);
        int d2 = (i2 > j2) ? (i2 - j2) : (j2 - i2);
        int c2 = (d2 <= 3) ? (d2 - 1) : 3;
        rank += (c2 == cls);
      }
      perm[C_OFF[cls] + rank] = e;
    }
    return;
  }
  b -= 1;
  {                                     // ---- out[EE..3EE] = float(ei) ----
    int idx = b * 256 + tid;
    if (idx < 2 * EE) out[EE + idx] = (float)ei[idx];
  }
}

// ------- fused edge embedding: 8-wave split, 64-row tile, 4 blocks/CU -------
// launch_bounds (512,8): LDS 35,328B x4 = 141KB <= 160KB; VGPR cap 64 (uses ~40)
__global__ __launch_bounds__(512, 8) void k_edge_attr(
    const float* __restrict__ pos, const int* __restrict__ ei,
    const float* __restrict__ eeW1, const float* __restrict__ eeb1,
    const float* __restrict__ ecb2,
    const bf16_t* __restrict__ wfoldT, const float* __restrict__ bfold,
    const int* __restrict__ perm,
    const bf16_t* __restrict__ WT, bf16_t* __restrict__ eattr, float* out) {
  __shared__ bf16_t B0[64 * 256];
  __shared__ float sW1f[256], sB1f[256];
  __shared__ int sE[64], sP[64];
  const int tid = threadIdx.x, lane = tid & 63, wave = tid >> 6;
  const int l15 = lane & 15, quad = lane >> 4;
  const int b = blockIdx.x;
  int cls, base;
  if (b < 150)      { cls = 0; base = b; }
  else if (b < 294) { cls = 1; base = b - 150; }
  else if (b < 432) { cls = 2; base = b - 294; }
  else              { cls = 3; base = b - 432; }
  const int cnt = C_CNT[cls], off = C_OFF[cls];

  if (tid < 256) { sW1f[tid] = eeW1[tid]; sB1f[tid] = eeb1[tid]; }
  if (tid < 64) {
    int slot = base * 64 + tid;
    int e = -1, p = 0;
    if (slot < cnt * 200) {
      int m = slot / cnt;
      int rr = slot - m * cnt;
      int eloc = perm[off + rr];
      e = m * 600 + eloc;
      p = eperm(e);
    }
    sE[tid] = e;
    sP[tid] = p;
  }
  __syncthreads();
  {
    int r = tid >> 3, cb = (tid & 7) * 32;
    int e = sE[r];
    float dd = 0.f;
    if (e >= 0) {
      int s = ei[e], dn = ei[EE + e];
      float d0 = pos[dn * 3 + 0] - pos[s * 3 + 0];
      float d1 = pos[dn * 3 + 1] - pos[s * 3 + 1];
      float d2 = pos[dn * 3 + 2] - pos[s * 3 + 2];
      dd = sqrtf(d0 * d0 + d1 * d1 + d2 * d2);
      if ((tid & 7) == 0) out[3 * EE + e] = dd;
    }
#pragma unroll
    for (int g = 0; g < 4; ++g) {
      int c0 = cb + g * 8;
      bf16x8 v;
#pragma unroll
      for (int q = 0; q < 8; ++q)
        v[q] = (bf16_t)silu_f(dd * sW1f[c0 + q] + sB1f[c0 + q]);
      *(bf16x8*)(B0 + swz(r, c0)) = v;
    }
  }
  __syncthreads();
  f32x4 acc[4][2];
  zacc(acc);
  gemm_lds<4, 2, 8>(B0, wfoldT + cls * 65536, 256, wave * 32, acc, lane);
  __syncthreads();
  {
    const float* bf = bfold + cls * 256;
    float bv[2];
#pragma unroll
    for (int nt = 0; nt < 2; ++nt) bv[nt] = bf[wave * 32 + nt * 16 + l15];
#pragma unroll
    for (int rt = 0; rt < 4; ++rt)
#pragma unroll
      for (int reg = 0; reg < 4; ++reg) {
        int r = rt * 16 + quad * 4 + reg;
#pragma unroll
        for (int nt = 0; nt < 2; ++nt) {
          int col = wave * 32 + nt * 16 + l15;
          B0[swz(r, col)] = (bf16_t)silu_f(acc[rt][nt][reg] + bv[nt]);
        }
      }
  }
  __syncthreads();
  zacc(acc);
  gemm_lds<4, 2, 8>(B0, WT + OFF_ECW2T, 256, wave * 32, acc, lane);
#pragma unroll
  for (int rt = 0; rt < 4; ++rt)
#pragma unroll
    for (int reg = 0; reg < 4; ++reg) {
      int r = rt * 16 + quad * 4 + reg;
      if (sE[r] >= 0) {
        int p = sP[r];
#pragma unroll
        for (int nt = 0; nt < 2; ++nt) {
          int col = wave * 32 + nt * 16 + l15;
          eattr[(size_t)p * 256 + col] = (bf16_t)(acc[rt][nt][reg] + ecb2[col]);
        }
      }
    }
}

// ------- message + segment-sum v11: 120-row tile (5 dst/block), grid 1000 -------
__global__ __launch_bounds__(512, 4) void k_msg(
    const bf16_t* __restrict__ eattr, const bf16_t* __restrict__ hl_g,
    const bf16_t* __restrict__ fW1T, const bf16_t* __restrict__ fW2T,
    const float* __restrict__ fb1, const float* __restrict__ fb2,
    bf16_t* __restrict__ agg) {
  __shared__ bf16_t buf[128 * 256];    // 64 KB
  __shared__ bf16_t hlb[26 * 264];     // 13.7 KB; row 25 = zeros
  __shared__ int sIdx[128];
  const int tid = threadIdx.x, lane = tid & 63, wave = tid >> 6;
  const int l15 = lane & 15, quad = lane >> 4;
  const int bid = blockIdx.x, m = bid / 5, p = bid % 5;
  const int j0 = p * 5;                // 5 dst nodes: j0..j0+4 (25 = 5*5 exact)
  const int pBase = m * 600 + j0 * 24; // contiguous 120 rows in dst-major eattr

  // async-stage 128 rows (120 valid + 8 dummy clamped to rows 0-7; gate 0)
  for (int it = wave; it < 64; it += 8) {
    int C = it * 64 + lane;            // chunk id 0..4095
    int r = C >> 5, kcs = C & 31;
    int rv = (r < 120) ? r : (r - 120);
    async16(buf + it * 512,
            eattr + (size_t)(pBase + rv) * 256 + ((kcs ^ (r & 7)) << 3));
  }
  // stage molecule's 25 hl rows + zero row 25
  for (int task = tid; task < 26 * 32; task += 512) {
    int i = task >> 5, kc = task & 31;
    bf16x8 v = (i < 25) ? *(const bf16x8*)(hl_g + (size_t)(m * 25 + i) * 256 + kc * 8)
                        : zero8();
    *(bf16x8*)(hlb + i * 264 + kc * 8) = v;
  }
  // precompute hlb row index per tile row
  if (tid < 128) {
    int r = tid;
    if (r < 120) {
      int g = r / 24, rr = r - g * 24, j = j0 + g;
      sIdx[r] = rr + (rr >= j);
    } else {
      sIdx[r] = 25;                    // zero gate for dummy rows
    }
  }
  __syncthreads();
  f32x4 acc[8][2];
  zacc(acc);
  gemm_lds<8, 2, 8>(buf, fW1T, 256, wave * 32, acc, lane);
  __syncthreads();
  {
    float b1[2];
#pragma unroll
    for (int nt = 0; nt < 2; ++nt) b1[nt] = fb1[wave * 32 + nt * 16 + l15];
#pragma unroll
    for (int rt = 0; rt < 8; ++rt)
#pragma unroll
      for (int reg = 0; reg < 4; ++reg) {
        int r = rt * 16 + quad * 4 + reg;
#pragma unroll
        for (int nt = 0; nt < 2; ++nt) {
          int c = wave * 32 + nt * 16 + l15;
          buf[swz(r, c)] = (bf16_t)ssp_f(acc[rt][nt][reg] + b1[nt]);
        }
      }
  }
  __syncthreads();
  zacc(acc);
  gemm_lds<8, 2, 8>(buf, fW2T, 256, wave * 32, acc, lane);
  // gated reduce into 5 dst buckets (compile-time bucket selection per rt)
  float s[5][2];
#pragma unroll
  for (int g = 0; g < 5; ++g) { s[g][0] = 0.f; s[g][1] = 0.f; }
#pragma unroll
  for (int nt = 0; nt < 2; ++nt) {
    int c = wave * 32 + nt * 16 + l15;
    float fb2c = fb2[c];
#pragma unroll
    for (int rt = 0; rt < 8; ++rt) {
      const int g0 = (rt * 16) / 24;           // compile-time
      const int bnd = (g0 + 1) * 24;
      const int g1 = (g0 < 4) ? (g0 + 1) : 4;  // dummy rows fold into bucket 4
#pragma unroll
      for (int reg = 0; reg < 4; ++reg) {
        int r = rt * 16 + quad * 4 + reg;
        float contrib = (acc[rt][nt][reg] + fb2c) * (float)hlb[sIdx[r] * 264 + c];
        if (r < bnd) s[g0][nt] += contrib; else s[g1][nt] += contrib;
      }
    }
  }
#pragma unroll
  for (int g = 0; g < 5; ++g)
#pragma unroll
    for (int nt = 0; nt < 2; ++nt) {
      float v = s[g][nt];
      v += __shfl_xor(v, 16);
      v += __shfl_xor(v, 32);
      s[g][nt] = v;
    }
  if (quad == 0) {
#pragma unroll
    for (int g = 0; g < 5; ++g)
#pragma unroll
      for (int nt = 0; nt < 2; ++nt) {
        int c = wave * 32 + nt * 16 + l15;
        agg[(size_t)(m * 25 + j0 + g) * 256 + c] = (bf16_t)s[g][nt];
      }
  }
}

// -------- fused: h += ssp(agg @ lin2 + b); optionally hl = h @ lin1 --------
// 32 nodes/block (grid 157): halves weight refetch vs 16-node version
__global__ __launch_bounds__(256) void k_updlin(
    const bf16_t* __restrict__ agg, const bf16_t* __restrict__ lin2T,
    const float* __restrict__ lin2b, bf16_t* h16,
    const bf16_t* __restrict__ lin1T, bf16_t* __restrict__ hl, int do_lin1) {
  __shared__ bf16_t buf[32 * 256];
  __shared__ bf16_t hbuf[32 * 256];
  const int tid = threadIdx.x, lane = tid & 63, wave = tid >> 6;
  const int l15 = lane & 15, quad = lane >> 4;
  const int row0 = blockIdx.x * 32;
  // async-stage agg + h rows (pad rows clamp to node NN-1; outputs guarded)
  for (int it = wave; it < 16; it += 4) {
    int C = it * 64 + lane;
    int r = C >> 5, kcs = C & 31;
    int node = row0 + r;
    size_t rowoff = (size_t)(node < NN ? node : NN - 1) * 256 + ((kcs ^ (r & 7)) << 3);
    async16(buf + it * 512, agg + rowoff);
    async16(hbuf + it * 512, h16 + rowoff);
  }
  __syncthreads();
  f32x4 acc[2][4];
  zacc(acc);
  gemm_lds<2, 4, 8>(buf, lin2T, 256, wave * 64, acc, lane);
  {
    float b2[4];
#pragma unroll
    for (int nt = 0; nt < 4; ++nt) b2[nt] = lin2b[wave * 64 + nt * 16 + l15];
#pragma unroll
    for (int rt = 0; rt < 2; ++rt)
#pragma unroll
      for (int reg = 0; reg < 4; ++reg) {
        int r = rt * 16 + quad * 4 + reg, node = row0 + r;
#pragma unroll
        for (int nt = 0; nt < 4; ++nt) {
          int c = wave * 64 + nt * 16 + l15;
          int idx = swz(r, c);
          float hn = (float)hbuf[idx] + ssp_f(acc[rt][nt][reg] + b2[nt]);
          bf16_t hb = (bf16_t)hn;
          hbuf[idx] = hb;
          if (node < NN) h16[(size_t)node * 256 + c] = hb;
        }
      }
  }
  if (!do_lin1) return;
  __syncthreads();
  f32x4 acc2[2][4];
  zacc(acc2);
  gemm_lds<2, 4, 8>(hbuf, lin1T, 256, wave * 64, acc2, lane);
#pragma unroll
  for (int rt = 0; rt < 2; ++rt)
#pragma unroll
    for (int reg = 0; reg < 4; ++reg) {
      int r = rt * 16 + quad * 4 + reg, node = row0 + r;
      if (node < NN) {
#pragma unroll
        for (int nt = 0; nt < 4; ++nt) {
          int c = wave * 64 + nt * 16 + l15;
          hl[(size_t)node * 256 + c] = (bf16_t)acc2[rt][nt][reg];
        }
      }
    }
}

// ---------------- hl = h @ lin1 (no bias), initial ----------------
__global__ __launch_bounds__(256) void k_lin1(
    const bf16_t* __restrict__ h16, const bf16_t* __restrict__ lin1T,
    bf16_t* __restrict__ hl) {
  __shared__ bf16_t buf[32 * 256];
  const int tid = threadIdx.x, lane = tid & 63, wave = tid >> 6;
  const int l15 = lane & 15, quad = lane >> 4;
  const int row0 = blockIdx.x * 32;
  for (int it = wave; it < 16; it += 4) {
    int C = it * 64 + lane;
    int r = C >> 5, kcs = C & 31;
    int node = row0 + r;
    async16(buf + it * 512,
            h16 + (size_t)(node < NN ? node : NN - 1) * 256 + ((kcs ^ (r & 7)) << 3));
  }
  __syncthreads();
  f32x4 acc[2][4];
  zacc(acc);
  gemm_lds<2, 4, 8>(buf, lin1T, 256, wave * 64, acc, lane);
#pragma unroll
  for (int rt = 0; rt < 2; ++rt)
#pragma unroll
    for (int reg = 0; reg < 4; ++reg) {
      int r = rt * 16 + quad * 4 + reg, node = row0 + r;
      if (node < NN) {
#pragma unroll
        for (int nt = 0; nt < 4; ++nt) {
          int c = wave * 64 + nt * 16 + l15;
          hl[(size_t)node * 256 + c] = (bf16_t)acc[rt][nt][reg];
        }
      }
    }
}

// ------- output head: dual-buffer, eattr async under GEMM1a (index copy moved out) -------
__global__ __launch_bounds__(512, 4) void k_head(
    const bf16_t* __restrict__ h16, const bf16_t* __restrict__ eattr, const int* ei,
    const float* gb1, const float* gb2, const float* gW3, const float* gb3,
    const bf16_t* WT, float* out) {
  __shared__ bf16_t B0[64 * 256];      // h_src * h_dst  (K 0-255)
  __shared__ bf16_t B1[64 * 256];      // eattr          (K 256-511)
  __shared__ int sP[64];
  const int tid = threadIdx.x, lane = tid & 63, wave = tid >> 6;
  const int l15 = lane & 15, quad = lane >> 4;
  const int eBase = blockIdx.x * 64;
  const int colB = wave * 32;

  if (tid < 64) sP[tid] = eperm(eBase + tid);
  for (int task = tid; task < 64 * 32; task += 512) {
    int r = task >> 5, kc = task & 31;
    int e = eBase + r, s = ei[e], dn = ei[EE + e];
    bf16x8 a = *(const bf16x8*)(h16 + (size_t)s * 256 + kc * 8);
    bf16x8 b = *(const bf16x8*)(h16 + (size_t)dn * 256 + kc * 8);
    bf16x8 v;
#pragma unroll
    for (int q = 0; q < 8; ++q) v[q] = (bf16_t)((float)a[q] * (float)b[q]);
    *(bf16x8*)(B0 + r * 256 + ((kc ^ (r & 7)) << 3)) = v;
  }
  __syncthreads();
  // issue eattr async-stage into B1 NOW; GEMM1a's 128 MFMA hide the latency,
  // and the next barrier's vmcnt drain guarantees completion before G1b.
  for (int it = wave; it < 32; it += 8) {
    int C = it * 64 + lane;
    int r = C >> 5, kcs = C & 31;
    async16(B1 + it * 512,
            eattr + (size_t)sP[r] * 256 + ((kcs ^ (r & 7)) << 3));
  }
  f32x4 acc1[4][2];
  zacc(acc1);
  gemm_lds<4, 2, 8>(B0, WT + OFF_GW1T, 512, colB, acc1, lane);
  __syncthreads();
  gemm_lds<4, 2, 8>(B1, WT + OFF_GW1T + 256, 512, colB, acc1, lane);
  // no barrier: epilogue writes B0 only; G1b reads B1 only.
  {
    float b1v[2];
#pragma unroll
    for (int nt = 0; nt < 2; ++nt) b1v[nt] = gb1[colB + nt * 16 + l15];
#pragma unroll
    for (int rt = 0; rt < 4; ++rt)
#pragma unroll
      for (int reg = 0; reg < 4; ++reg) {
        int r = rt * 16 + quad * 4 + reg;
#pragma unroll
        for (int nt = 0; nt < 2; ++nt) {
          int c = colB + nt * 16 + l15;
          B0[swz(r, c)] = (bf16_t)silu_f(acc1[rt][nt][reg] + b1v[nt]);
        }
      }
  }
  __syncthreads();
  f32x4 acc2[4][1];
  zacc(acc2);
  gemm_lds<4, 1, 8>(B0, WT + OFF_GW2T, 256, wave * 16, acc2, lane);
  __syncthreads();
  {
    float b2v = gb2[wave * 16 + l15];
#pragma unroll
    for (int rt = 0; rt < 4; ++rt)
#pragma unroll
      for (int reg = 0; reg < 4; ++reg) {
        int r = rt * 16 + quad * 4 + reg;
        int c = wave * 16 + l15;
        B0[swz(r, c)] = (bf16_t)silu_f(acc2[rt][0][reg] + b2v);
      }
  }
  __syncthreads();
  {
    // vectorized final dot over 128 cols: 2 x ds_read_b128 + 4 x f32x4 per thread
    int r = tid >> 3, part = tid & 7;
    float s = 0.f;
#pragma unroll
    for (int g = 0; g < 2; ++g) {
      int chunk = part * 2 + g;                       // col chunk (c = chunk*8+q)
      const bf16x8 v = *(const bf16x8*)(B0 + r * 256 + ((chunk ^ (r & 7)) << 3));
      const f32x4 w0 = *(const f32x4*)(gW3 + part * 16 + g * 8);
      const f32x4 w1 = *(const f32x4*)(gW3 + part * 16 + g * 8 + 4);
#pragma unroll
      for (int q = 0; q < 4; ++q) s += (float)v[q] * w0[q];
#pragma unroll
      for (int q = 0; q < 4; ++q) s += (float)v[4 + q] * w1[q];
    }
    s += __shfl_xor(s, 1);
    s += __shfl_xor(s, 2);
    s += __shfl_xor(s, 4);
    if (part == 0) out[eBase + r] = s + gb3[0];
  }
}

extern "C" void kernel_launch(void* const* d_in, const int* in_sizes, int n_in,
                              void* d_out, int out_size, void* d_ws, size_t ws_size,
                              hipStream_t stream) {
  const float* pos   = (const float*)d_in[0];
  const float* rfeat = (const float*)d_in[1];
  const float* pfeat = (const float*)d_in[2];
  const float* emb   = (const float*)d_in[3];
  const float* Wf    = (const float*)d_in[4];
  const float* bemb  = (const float*)d_in[5];
  const float* eeW1  = (const float*)d_in[6];
  const float* eeb1  = (const float*)d_in[7];
  const float* eeW2  = (const float*)d_in[8];
  const float* eeb2  = (const float*)d_in[9];
  const float* ecW1  = (const float*)d_in[10];
  const float* ecb1  = (const float*)d_in[11];
  const float* ecW2  = (const float*)d_in[12];
  const float* ecb2  = (const float*)d_in[13];
  const float* fW1   = (const float*)d_in[14];
  const float* fb1   = (const float*)d_in[15];
  const float* fW2   = (const float*)d_in[16];
  const float* fb2   = (const float*)d_in[17];
  const float* ln1   = (const float*)d_in[18];
  const float* ln2   = (const float*)d_in[19];
  const float* ln2b  = (const float*)d_in[20];
  const float* gW1   = (const float*)d_in[21];
  const float* gb1   = (const float*)d_in[22];
  const float* gW2   = (const float*)d_in[23];
  const float* gb2   = (const float*)d_in[24];
  const float* gW3   = (const float*)d_in[25];
  const float* gb3   = (const float*)d_in[26];
  const int* atype = (const int*)d_in[27];
  const int* ei    = (const int*)d_in[28];
  const int* etr   = (const int*)d_in[29];
  const int* etp   = (const int*)d_in[30];
  (void)etr; (void)etp;

  float* out = (float*)d_out;
  char* ws = (char*)d_ws;
  bf16_t* WT     = (bf16_t*)(ws);
  bf16_t* h16    = (bf16_t*)(ws + WSOFF_H16);
  bf16_t* hl     = (bf16_t*)(ws + WSOFF_HL);
  bf16_t* agg    = (bf16_t*)(ws + WSOFF_AGG);
  bf16_t* eattr  = (bf16_t*)(ws + WSOFF_EATTR);
  bf16_t* wfoldT = (bf16_t*)(ws + WSOFF_AGG);                  // transient, pre-conv
  float*  bfold  = (float*)(ws + WSOFF_AGG + AGGOFF_BFOLD);    // transient
  int*    perm   = (int*)(ws + WSOFF_AGG + AGGOFF_PERM);       // transient

  // fused setup: transpose + fold + foldb + node + prep + out-index-copy
  k_setup<<<9459, 256, 0, stream>>>(eeW2, ecW1, ecW2, fW1, fW2, ln1, ln2, gW1, gW2, WT,
                                    bemb, eeb2, ecb1, wfoldT, bfold, perm,
                                    rfeat, pfeat, emb, Wf, atype, h16, ei, out);
  k_edge_attr<<<1876, 512, 0, stream>>>(pos, ei, eeW1, eeb1, ecb2,
                                        wfoldT, bfold, perm, WT, eattr, out);
  k_lin1<<<157, 256, 0, stream>>>(h16, WT + OFF_LN1T, hl);
  for (int l = 0; l < 4; ++l) {
    k_msg<<<1000, 512, 0, stream>>>(eattr, hl,
                                    WT + OFF_FW1T + l * 65536, WT + OFF_FW2T + l * 65536,
                                    fb1 + l * 256, fb2 + l * 256, agg);
    k_updlin<<<157, 256, 0, stream>>>(agg, WT + OFF_LN2T + l * 65536, ln2b + l * 256,
                                      h16, WT + OFF_LN1T + (l + 1 < 4 ? l + 1 : 0) * 65536,
                                      hl, l < 3 ? 1 : 0);
  }
  k_head<<<EE / 64, 512, 0, stream>>>(h16, eattr, ei, gb1, gb2, gW3, gb3, WT, out);
}

// Round 10
// 720.822 us; speedup vs baseline: 1.0785x; 1.0785x over previous
//
#include <hip/hip_runtime.h>

#define NN 5000
#define EE 120000

typedef __bf16 bf16_t;
typedef __bf16 bf16x8 __attribute__((ext_vector_type(8)));
typedef float f32x4 __attribute__((ext_vector_type(4)));

// W^T offsets (elements) inside ws
#define OFF_EEW2T 0
#define OFF_ECW1T 65536
#define OFF_ECW2T 196608
#define OFF_FW1T  262144
#define OFF_FW2T  524288
#define OFF_LN1T  786432
#define OFF_LN2T  1048576
#define OFF_GW1T  1310720
#define OFF_GW2T  1441792

// ws byte offsets (total 72,069,120 B — proven available)
#define WSOFF_H16   2949120
#define WSOFF_HL    5509120
#define WSOFF_AGG   8069120
#define WSOFF_EATTR 10629120
// transient region inside AGG (free until k_msg runs)
#define AGGOFF_BFOLD 524288
#define AGGOFF_PERM  528384

// edge-class metadata (within-molecule): order [d1, d2, d3, d>=4]
__device__ __constant__ int C_CNT[4] = {48, 46, 44, 462};
__device__ __constant__ int C_OFF[4] = {0, 48, 94, 138};

// XOR-swizzled [rows x 256] bf16 tile: 16B chunks permuted by row, conflict-free
__device__ __forceinline__ int swz(int r, int c) {
  return r * 256 + ((((c >> 3) ^ (r & 7)) << 3) | (c & 7));
}

__device__ __forceinline__ float silu_f(float x) { return x / (1.f + __expf(-x)); }
// fast shifted-softplus: native v_exp/v_log; |x| is O(1) here
__device__ __forceinline__ float ssp_f(float x) {
  return __logf(1.f + __expf(x)) - 0.6931472f;
}

// async global->LDS 16B copy: LDS dest = uniform base + lane*16 (HW),
// global source is per-lane (pre-swizzled to match the swizzled read layout)
__device__ __forceinline__ void async16(bf16_t* lds, const bf16_t* g) {
  __builtin_amdgcn_global_load_lds(
      (__attribute__((address_space(1))) const void*)g,
      (__attribute__((address_space(3))) void*)lds, 16, 0, 0);
}

// dst-major storage index for edge e (eattr is stored permuted):
// e = m*600 + i*24 + q, j = q + (q>=i)  ->  p = m*600 + j*24 + (i>j ? i-1 : i)
__device__ __forceinline__ int eperm(int e) {
  int m = e / 600, eloc = e - m * 600;
  int i = eloc / 24, q = eloc - i * 24;
  int j = q + (q >= i);
  return m * 600 + j * 24 + i - (i > j);
}

__device__ __forceinline__ bf16x8 zero8() {
  bf16x8 v;
#pragma unroll
  for (int q = 0; q < 8; ++q) v[q] = (__bf16)0.f;
  return v;
}

template<int RT, int NT>
__device__ __forceinline__ void zacc(f32x4 (&acc)[RT][NT]) {
#pragma unroll
  for (int i = 0; i < RT; ++i)
#pragma unroll
    for (int j = 0; j < NT; ++j) {
      f32x4 z = {0.f, 0.f, 0.f, 0.f};
      acc[i][j] = z;
    }
}

// A: LDS swizzled tile, rows rt*16+l15, k chunks ks*32+quad*8
// WT: global W^T [N, ldK] row-major (bf16); effective B[k][n] = WT[n*ldK + k]
template<int RT, int NT, int KS>
__device__ __forceinline__ void gemm_lds(const bf16_t* __restrict__ A,
                                         const bf16_t* __restrict__ WT, int ldK,
                                         int colBase, f32x4 (&acc)[RT][NT], int lane) {
  const int l15 = lane & 15, quad = lane >> 4;
#pragma unroll
  for (int ks = 0; ks < KS; ++ks) {
    const int kc = ks * 4 + quad;
    bf16x8 a[RT];
#pragma unroll
    for (int rt = 0; rt < RT; ++rt) {
      int r = rt * 16 + l15;
      a[rt] = *(const bf16x8*)(A + r * 256 + ((kc ^ (r & 7)) << 3));
    }
#pragma unroll
    for (int nt = 0; nt < NT; ++nt) {
      const bf16x8 b = *(const bf16x8*)(WT + (size_t)(colBase + nt * 16 + l15) * ldK + kc * 8);
#pragma unroll
      for (int rt = 0; rt < RT; ++rt)
        acc[rt][nt] = __builtin_amdgcn_mfma_f32_16x16x32_bf16(a[rt], b, acc[rt][nt], 0, 0, 0);
    }
  }
}

// -------- fused setup: transpose ∪ fold ∪ foldb ∪ node ∪ prep ∪ out-copy --------
// grid partition (flat blockIdx.x, 256 threads):
//   [0,4992)            weight transpose (1,277,952 elems)
//   [4992,6016)         k_fold (p = b>>8, k = b&255)
//   [6016,6020)         k_foldb (p = b)
//   [6020,8520)         node embedding (2 nodes / block)
//   [8520,8521)         perm builder
//   [8521,9459)         out[EE..3EE] = float(ei)  (240,000 elems)
// Every body is arithmetically identical to the former standalone kernel.
__global__ __launch_bounds__(256) void k_setup(
    const float* eeW2, const float* ecW1, const float* ecW2,
    const float* fW1, const float* fW2, const float* ln1, const float* ln2,
    const float* gW1, const float* gW2, bf16_t* WT,
    const float* bemb, const float* eeb2, const float* ecb1,
    bf16_t* wfoldT, float* bfold, int* perm,
    const float* r_feat, const float* p_feat, const float* emb, const float* Wf,
    const int* atype, bf16_t* h16, const int* ei, float* out) {
  __shared__ float rf[2][27], pf[2][27];
  const int tid = threadIdx.x;
  int b = blockIdx.x;
  if (b < 4992) {                       // ---- weight transpose ----
    int g = b * 256 + tid;
    if (g < 1114112) {                  // segs 0..16: K=256, Nn=256
      int seg = g >> 16, idx = g & 65535;
      const float* src; int off;
      if (seg == 0)       { src = ecW2;                    off = OFF_ECW2T; }
      else if (seg <= 4)  { src = fW1 + (seg - 1) * 65536; off = OFF_FW1T + (seg - 1) * 65536; }
      else if (seg <= 8)  { src = fW2 + (seg - 5) * 65536; off = OFF_FW2T + (seg - 5) * 65536; }
      else if (seg <= 12) { src = ln1 + (seg - 9) * 65536; off = OFF_LN1T + (seg - 9) * 65536; }
      else                { src = ln2 + (seg - 13) * 65536; off = OFF_LN2T + (seg - 13) * 65536; }
      int k = idx & 255, n = idx >> 8;
      WT[off + idx] = (bf16_t)src[k * 256 + n];
    } else if (g < 1245184) {           // seg 17: gW1, K=512, Nn=256
      int idx = g - 1114112;
      int k = idx & 511, n = idx >> 9;
      WT[OFF_GW1T + idx] = (bf16_t)gW1[k * 256 + n];
    } else if (g < 1277952) {           // seg 18: gW2, K=256, Nn=128
      int idx = g - 1245184;
      int k = idx & 255, n = idx >> 8;
      WT[OFF_GW2T + idx] = (bf16_t)gW2[k * 128 + n];
    }
    return;
  }
  b -= 4992;
  if (b < 1024) {                       // ---- k_fold ----
    const int p = b >> 8, k = b & 255, n = tid;
    const int TR[4] = {1, 2, 3, 0}, TP[4] = {3, 2, 1, 0};
    const float* br = bemb + TR[p] * 256;
    const float* bp = bemb + TP[p] * 256;
    float acc = 0.f;
    for (int m = 0; m < 256; ++m) {
      float wc = br[m] * ecW1[m * 256 + n] + bp[m] * ecW1[(256 + m) * 256 + n];
      acc += eeW2[k * 256 + m] * wc;
    }
    wfoldT[p * 65536 + n * 256 + k] = (bf16_t)acc;
    return;
  }
  b -= 1024;
  if (b < 4) {                          // ---- k_foldb ----
    const int p = b, n = tid;
    const int TR[4] = {1, 2, 3, 0}, TP[4] = {3, 2, 1, 0};
    const float* br = bemb + TR[p] * 256;
    const float* bp = bemb + TP[p] * 256;
    float acc = ecb1[n];
    for (int m = 0; m < 256; ++m) {
      float wc = br[m] * ecW1[m * 256 + n] + bp[m] * ecW1[(256 + m) * 256 + n];
      acc += eeb2[m] * wc;
    }
    bfold[p * 256 + n] = acc;
    return;
  }
  b -= 4;
  if (b < 2500) {                       // ---- node embedding, 2 nodes/block ----
    int half = tid >> 7, t = tid & 127;
    int n = b * 2 + half;
    if (t < 27) { rf[half][t] = r_feat[n * 27 + t]; pf[half][t] = p_feat[n * 27 + t]; }
    __syncthreads();
    float fr = 0.f, fp = 0.f;
#pragma unroll
    for (int k = 0; k < 27; ++k) {
      float w = Wf[k * 128 + t];
      fr += rf[half][k] * w; fp += pf[half][k] * w;
    }
    int at = atype[n];
    size_t base = (size_t)n * 256;
    h16[base + t] = (bf16_t)(emb[at * 128 + t] + fr);
    h16[base + 128 + t] = (bf16_t)(fp - fr);
    return;
  }
  b -= 2500;
  if (b < 1) {                          // ---- perm builder ----
    for (int e = tid; e < 600; e += 256) {
      int i = e / 24, q = e % 24;
      int j = q + (q >= i ? 1 : 0);
      int d = (i > j) ? (i - j) : (j - i);
      int cls = (d <= 3) ? (d - 1) : 3;
      int rank = 0;
      for (int e2 = 0; e2 < e; ++e2) {
        int i2 = e2 / 24, q2 = e2 % 24;
        int j2 = q2 + (q2 >= i2 ? 1 : 0);
        int d2 = (i2 > j2) ? (i2 - j2) : (j2 - i2);
        int c2 = (d2 <= 3) ? (d2 - 1) : 3;
        rank += (c2 == cls);
      }
      perm[C_OFF[cls] + rank] = e;
    }
    return;
  }
  b -= 1;
  {                                     // ---- out[EE..3EE] = float(ei) ----
    int idx = b * 256 + tid;
    if (idx < 2 * EE) out[EE + idx] = (float)ei[idx];
  }
}

// ------- fused edge embedding (proven r5/r8 config): 8-wave split, 64-row tile -------
// (512,6): 3 blocks/CU — measured optimum. (512,8) tripled FETCH via L2 thrash (r9).
__global__ __launch_bounds__(512, 6) void k_edge_attr(
    const float* __restrict__ pos, const int* __restrict__ ei,
    const float* __restrict__ eeW1, const float* __restrict__ eeb1,
    const float* __restrict__ ecb2,
    const bf16_t* __restrict__ wfoldT, const float* __restrict__ bfold,
    const int* __restrict__ perm,
    const bf16_t* __restrict__ WT, bf16_t* __restrict__ eattr, float* out) {
  __shared__ bf16_t B0[64 * 256];
  __shared__ float sW1f[256], sB1f[256];
  __shared__ int sE[64], sP[64];
  const int tid = threadIdx.x, lane = tid & 63, wave = tid >> 6;
  const int l15 = lane & 15, quad = lane >> 4;
  const int b = blockIdx.x;
  int cls, base;
  if (b < 150)      { cls = 0; base = b; }
  else if (b < 294) { cls = 1; base = b - 150; }
  else if (b < 432) { cls = 2; base = b - 294; }
  else              { cls = 3; base = b - 432; }
  const int cnt = C_CNT[cls], off = C_OFF[cls];

  if (tid < 256) { sW1f[tid] = eeW1[tid]; sB1f[tid] = eeb1[tid]; }
  if (tid < 64) {
    int slot = base * 64 + tid;
    int e = -1, p = 0;
    if (slot < cnt * 200) {
      int m = slot / cnt;
      int rr = slot - m * cnt;
      int eloc = perm[off + rr];
      e = m * 600 + eloc;
      p = eperm(e);
    }
    sE[tid] = e;
    sP[tid] = p;
  }
  __syncthreads();
  {
    int r = tid >> 3, cb = (tid & 7) * 32;
    int e = sE[r];
    float dd = 0.f;
    if (e >= 0) {
      int s = ei[e], dn = ei[EE + e];
      float d0 = pos[dn * 3 + 0] - pos[s * 3 + 0];
      float d1 = pos[dn * 3 + 1] - pos[s * 3 + 1];
      float d2 = pos[dn * 3 + 2] - pos[s * 3 + 2];
      dd = sqrtf(d0 * d0 + d1 * d1 + d2 * d2);
      if ((tid & 7) == 0) out[3 * EE + e] = dd;
    }
#pragma unroll
    for (int g = 0; g < 4; ++g) {
      int c0 = cb + g * 8;
      bf16x8 v;
#pragma unroll
      for (int q = 0; q < 8; ++q)
        v[q] = (bf16_t)silu_f(dd * sW1f[c0 + q] + sB1f[c0 + q]);
      *(bf16x8*)(B0 + swz(r, c0)) = v;
    }
  }
  __syncthreads();
  f32x4 acc[4][2];
  zacc(acc);
  gemm_lds<4, 2, 8>(B0, wfoldT + cls * 65536, 256, wave * 32, acc, lane);
  __syncthreads();
  {
    const float* bf = bfold + cls * 256;
    float bv[2];
#pragma unroll
    for (int nt = 0; nt < 2; ++nt) bv[nt] = bf[wave * 32 + nt * 16 + l15];
#pragma unroll
    for (int rt = 0; rt < 4; ++rt)
#pragma unroll
      for (int reg = 0; reg < 4; ++reg) {
        int r = rt * 16 + quad * 4 + reg;
#pragma unroll
        for (int nt = 0; nt < 2; ++nt) {
          int col = wave * 32 + nt * 16 + l15;
          B0[swz(r, col)] = (bf16_t)silu_f(acc[rt][nt][reg] + bv[nt]);
        }
      }
  }
  __syncthreads();
  zacc(acc);
  gemm_lds<4, 2, 8>(B0, WT + OFF_ECW2T, 256, wave * 32, acc, lane);
#pragma unroll
  for (int rt = 0; rt < 4; ++rt)
#pragma unroll
    for (int reg = 0; reg < 4; ++reg) {
      int r = rt * 16 + quad * 4 + reg;
      if (sE[r] >= 0) {
        int p = sP[r];
#pragma unroll
        for (int nt = 0; nt < 2; ++nt) {
          int col = wave * 32 + nt * 16 + l15;
          eattr[(size_t)p * 256 + col] = (bf16_t)(acc[rt][nt][reg] + ecb2[col]);
        }
      }
    }
}

// ------- message + segment-sum v11: 120-row tile (5 dst/block), grid 1000 -------
__global__ __launch_bounds__(512, 4) void k_msg(
    const bf16_t* __restrict__ eattr, const bf16_t* __restrict__ hl_g,
    const bf16_t* __restrict__ fW1T, const bf16_t* __restrict__ fW2T,
    const float* __restrict__ fb1, const float* __restrict__ fb2,
    bf16_t* __restrict__ agg) {
  __shared__ bf16_t buf[128 * 256];    // 64 KB
  __shared__ bf16_t hlb[26 * 264];     // 13.7 KB; row 25 = zeros
  __shared__ int sIdx[128];
  const int tid = threadIdx.x, lane = tid & 63, wave = tid >> 6;
  const int l15 = lane & 15, quad = lane >> 4;
  const int bid = blockIdx.x, m = bid / 5, p = bid % 5;
  const int j0 = p * 5;                // 5 dst nodes: j0..j0+4 (25 = 5*5 exact)
  const int pBase = m * 600 + j0 * 24; // contiguous 120 rows in dst-major eattr

  // async-stage 128 rows (120 valid + 8 dummy clamped to rows 0-7; gate 0)
  for (int it = wave; it < 64; it += 8) {
    int C = it * 64 + lane;            // chunk id 0..4095
    int r = C >> 5, kcs = C & 31;
    int rv = (r < 120) ? r : (r - 120);
    async16(buf + it * 512,
            eattr + (size_t)(pBase + rv) * 256 + ((kcs ^ (r & 7)) << 3));
  }
  // stage molecule's 25 hl rows + zero row 25
  for (int task = tid; task < 26 * 32; task += 512) {
    int i = task >> 5, kc = task & 31;
    bf16x8 v = (i < 25) ? *(const bf16x8*)(hl_g + (size_t)(m * 25 + i) * 256 + kc * 8)
                        : zero8();
    *(bf16x8*)(hlb + i * 264 + kc * 8) = v;
  }
  // precompute hlb row index per tile row
  if (tid < 128) {
    int r = tid;
    if (r < 120) {
      int g = r / 24, rr = r - g * 24, j = j0 + g;
      sIdx[r] = rr + (rr >= j);
    } else {
      sIdx[r] = 25;                    // zero gate for dummy rows
    }
  }
  __syncthreads();
  f32x4 acc[8][2];
  zacc(acc);
  gemm_lds<8, 2, 8>(buf, fW1T, 256, wave * 32, acc, lane);
  __syncthreads();
  {
    float b1[2];
#pragma unroll
    for (int nt = 0; nt < 2; ++nt) b1[nt] = fb1[wave * 32 + nt * 16 + l15];
#pragma unroll
    for (int rt = 0; rt < 8; ++rt)
#pragma unroll
      for (int reg = 0; reg < 4; ++reg) {
        int r = rt * 16 + quad * 4 + reg;
#pragma unroll
        for (int nt = 0; nt < 2; ++nt) {
          int c = wave * 32 + nt * 16 + l15;
          buf[swz(r, c)] = (bf16_t)ssp_f(acc[rt][nt][reg] + b1[nt]);
        }
      }
  }
  __syncthreads();
  zacc(acc);
  gemm_lds<8, 2, 8>(buf, fW2T, 256, wave * 32, acc, lane);
  // gated reduce into 5 dst buckets (compile-time bucket selection per rt)
  float s[5][2];
#pragma unroll
  for (int g = 0; g < 5; ++g) { s[g][0] = 0.f; s[g][1] = 0.f; }
#pragma unroll
  for (int nt = 0; nt < 2; ++nt) {
    int c = wave * 32 + nt * 16 + l15;
    float fb2c = fb2[c];
#pragma unroll
    for (int rt = 0; rt < 8; ++rt) {
      const int g0 = (rt * 16) / 24;           // compile-time
      const int bnd = (g0 + 1) * 24;
      const int g1 = (g0 < 4) ? (g0 + 1) : 4;  // dummy rows fold into bucket 4
#pragma unroll
      for (int reg = 0; reg < 4; ++reg) {
        int r = rt * 16 + quad * 4 + reg;
        float contrib = (acc[rt][nt][reg] + fb2c) * (float)hlb[sIdx[r] * 264 + c];
        if (r < bnd) s[g0][nt] += contrib; else s[g1][nt] += contrib;
      }
    }
  }
#pragma unroll
  for (int g = 0; g < 5; ++g)
#pragma unroll
    for (int nt = 0; nt < 2; ++nt) {
      float v = s[g][nt];
      v += __shfl_xor(v, 16);
      v += __shfl_xor(v, 32);
      s[g][nt] = v;
    }
  if (quad == 0) {
#pragma unroll
    for (int g = 0; g < 5; ++g)
#pragma unroll
      for (int nt = 0; nt < 2; ++nt) {
        int c = wave * 32 + nt * 16 + l15;
        agg[(size_t)(m * 25 + j0 + g) * 256 + c] = (bf16_t)s[g][nt];
      }
  }
}

// -------- fused: h += ssp(agg @ lin2 + b); optionally hl = h @ lin1 --------
// 32 nodes/block (grid 157): halves weight refetch vs 16-node version
__global__ __launch_bounds__(256) void k_updlin(
    const bf16_t* __restrict__ agg, const bf16_t* __restrict__ lin2T,
    const float* __restrict__ lin2b, bf16_t* h16,
    const bf16_t* __restrict__ lin1T, bf16_t* __restrict__ hl, int do_lin1) {
  __shared__ bf16_t buf[32 * 256];
  __shared__ bf16_t hbuf[32 * 256];
  const int tid = threadIdx.x, lane = tid & 63, wave = tid >> 6;
  const int l15 = lane & 15, quad = lane >> 4;
  const int row0 = blockIdx.x * 32;
  // async-stage agg + h rows (pad rows clamp to node NN-1; outputs guarded)
  for (int it = wave; it < 16; it += 4) {
    int C = it * 64 + lane;
    int r = C >> 5, kcs = C & 31;
    int node = row0 + r;
    size_t rowoff = (size_t)(node < NN ? node : NN - 1) * 256 + ((kcs ^ (r & 7)) << 3);
    async16(buf + it * 512, agg + rowoff);
    async16(hbuf + it * 512, h16 + rowoff);
  }
  __syncthreads();
  f32x4 acc[2][4];
  zacc(acc);
  gemm_lds<2, 4, 8>(buf, lin2T, 256, wave * 64, acc, lane);
  {
    float b2[4];
#pragma unroll
    for (int nt = 0; nt < 4; ++nt) b2[nt] = lin2b[wave * 64 + nt * 16 + l15];
#pragma unroll
    for (int rt = 0; rt < 2; ++rt)
#pragma unroll
      for (int reg = 0; reg < 4; ++reg) {
        int r = rt * 16 + quad * 4 + reg, node = row0 + r;
#pragma unroll
        for (int nt = 0; nt < 4; ++nt) {
          int c = wave * 64 + nt * 16 + l15;
          int idx = swz(r, c);
          float hn = (float)hbuf[idx] + ssp_f(acc[rt][nt][reg] + b2[nt]);
          bf16_t hb = (bf16_t)hn;
          hbuf[idx] = hb;
          if (node < NN) h16[(size_t)node * 256 + c] = hb;
        }
      }
  }
  if (!do_lin1) return;
  __syncthreads();
  f32x4 acc2[2][4];
  zacc(acc2);
  gemm_lds<2, 4, 8>(hbuf, lin1T, 256, wave * 64, acc2, lane);
#pragma unroll
  for (int rt = 0; rt < 2; ++rt)
#pragma unroll
    for (int reg = 0; reg < 4; ++reg) {
      int r = rt * 16 + quad * 4 + reg, node = row0 + r;
      if (node < NN) {
#pragma unroll
        for (int nt = 0; nt < 4; ++nt) {
          int c = wave * 64 + nt * 16 + l15;
          hl[(size_t)node * 256 + c] = (bf16_t)acc2[rt][nt][reg];
        }
      }
    }
}

// ---------------- hl = h @ lin1 (no bias), initial ----------------
__global__ __launch_bounds__(256) void k_lin1(
    const bf16_t* __restrict__ h16, const bf16_t* __restrict__ lin1T,
    bf16_t* __restrict__ hl) {
  __shared__ bf16_t buf[32 * 256];
  const int tid = threadIdx.x, lane = tid & 63, wave = tid >> 6;
  const int l15 = lane & 15, quad = lane >> 4;
  const int row0 = blockIdx.x * 32;
  for (int it = wave; it < 16; it += 4) {
    int C = it * 64 + lane;
    int r = C >> 5, kcs = C & 31;
    int node = row0 + r;
    async16(buf + it * 512,
            h16 + (size_t)(node < NN ? node : NN - 1) * 256 + ((kcs ^ (r & 7)) << 3));
  }
  __syncthreads();
  f32x4 acc[2][4];
  zacc(acc);
  gemm_lds<2, 4, 8>(buf, lin1T, 256, wave * 64, acc, lane);
#pragma unroll
  for (int rt = 0; rt < 2; ++rt)
#pragma unroll
    for (int reg = 0; reg < 4; ++reg) {
      int r = rt * 16 + quad * 4 + reg, node = row0 + r;
      if (node < NN) {
#pragma unroll
        for (int nt = 0; nt < 4; ++nt) {
          int c = wave * 64 + nt * 16 + l15;
          hl[(size_t)node * 256 + c] = (bf16_t)acc[rt][nt][reg];
        }
      }
    }
}

// ------- output head: dual-buffer, eattr async under GEMM1a (index copy moved out) -------
__global__ __launch_bounds__(512, 4) void k_head(
    const bf16_t* __restrict__ h16, const bf16_t* __restrict__ eattr, const int* ei,
    const float* gb1, const float* gb2, const float* gW3, const float* gb3,
    const bf16_t* WT, float* out) {
  __shared__ bf16_t B0[64 * 256];      // h_src * h_dst  (K 0-255)
  __shared__ bf16_t B1[64 * 256];      // eattr          (K 256-511)
  __shared__ int sP[64];
  const int tid = threadIdx.x, lane = tid & 63, wave = tid >> 6;
  const int l15 = lane & 15, quad = lane >> 4;
  const int eBase = blockIdx.x * 64;
  const int colB = wave * 32;

  if (tid < 64) sP[tid] = eperm(eBase + tid);
  for (int task = tid; task < 64 * 32; task += 512) {
    int r = task >> 5, kc = task & 31;
    int e = eBase + r, s = ei[e], dn = ei[EE + e];
    bf16x8 a = *(const bf16x8*)(h16 + (size_t)s * 256 + kc * 8);
    bf16x8 b = *(const bf16x8*)(h16 + (size_t)dn * 256 + kc * 8);
    bf16x8 v;
#pragma unroll
    for (int q = 0; q < 8; ++q) v[q] = (bf16_t)((float)a[q] * (float)b[q]);
    *(bf16x8*)(B0 + r * 256 + ((kc ^ (r & 7)) << 3)) = v;
  }
  __syncthreads();
  // issue eattr async-stage into B1 NOW; GEMM1a's 128 MFMA hide the latency,
  // and the next barrier's vmcnt drain guarantees completion before G1b.
  for (int it = wave; it < 32; it += 8) {
    int C = it * 64 + lane;
    int r = C >> 5, kcs = C & 31;
    async16(B1 + it * 512,
            eattr + (size_t)sP[r] * 256 + ((kcs ^ (r & 7)) << 3));
  }
  f32x4 acc1[4][2];
  zacc(acc1);
  gemm_lds<4, 2, 8>(B0, WT + OFF_GW1T, 512, colB, acc1, lane);
  __syncthreads();
  gemm_lds<4, 2, 8>(B1, WT + OFF_GW1T + 256, 512, colB, acc1, lane);
  // no barrier: epilogue writes B0 only; G1b reads B1 only.
  {
    float b1v[2];
#pragma unroll
    for (int nt = 0; nt < 2; ++nt) b1v[nt] = gb1[colB + nt * 16 + l15];
#pragma unroll
    for (int rt = 0; rt < 4; ++rt)
#pragma unroll
      for (int reg = 0; reg < 4; ++reg) {
        int r = rt * 16 + quad * 4 + reg;
#pragma unroll
        for (int nt = 0; nt < 2; ++nt) {
          int c = colB + nt * 16 + l15;
          B0[swz(r, c)] = (bf16_t)silu_f(acc1[rt][nt][reg] + b1v[nt]);
        }
      }
  }
  __syncthreads();
  f32x4 acc2[4][1];
  zacc(acc2);
  gemm_lds<4, 1, 8>(B0, WT + OFF_GW2T, 256, wave * 16, acc2, lane);
  __syncthreads();
  {
    float b2v = gb2[wave * 16 + l15];
#pragma unroll
    for (int rt = 0; rt < 4; ++rt)
#pragma unroll
      for (int reg = 0; reg < 4; ++reg) {
        int r = rt * 16 + quad * 4 + reg;
        int c = wave * 16 + l15;
        B0[swz(r, c)] = (bf16_t)silu_f(acc2[rt][0][reg] + b2v);
      }
  }
  __syncthreads();
  {
    // vectorized final dot over 128 cols: 2 x ds_read_b128 + 4 x f32x4 per thread
    int r = tid >> 3, part = tid & 7;
    float s = 0.f;
#pragma unroll
    for (int g = 0; g < 2; ++g) {
      int chunk = part * 2 + g;                       // col chunk (c = chunk*8+q)
      const bf16x8 v = *(const bf16x8*)(B0 + r * 256 + ((chunk ^ (r & 7)) << 3));
      const f32x4 w0 = *(const f32x4*)(gW3 + part * 16 + g * 8);
      const f32x4 w1 = *(const f32x4*)(gW3 + part * 16 + g * 8 + 4);
#pragma unroll
      for (int q = 0; q < 4; ++q) s += (float)v[q] * w0[q];
#pragma unroll
      for (int q = 0; q < 4; ++q) s += (float)v[4 + q] * w1[q];
    }
    s += __shfl_xor(s, 1);
    s += __shfl_xor(s, 2);
    s += __shfl_xor(s, 4);
    if (part == 0) out[eBase + r] = s + gb3[0];
  }
}

extern "C" void kernel_launch(void* const* d_in, const int* in_sizes, int n_in,
                              void* d_out, int out_size, void* d_ws, size_t ws_size,
                              hipStream_t stream) {
  const float* pos   = (const float*)d_in[0];
  const float* rfeat = (const float*)d_in[1];
  const float* pfeat = (const float*)d_in[2];
  const float* emb   = (const float*)d_in[3];
  const float* Wf    = (const float*)d_in[4];
  const float* bemb  = (const float*)d_in[5];
  const float* eeW1  = (const float*)d_in[6];
  const float* eeb1  = (const float*)d_in[7];
  const float* eeW2  = (const float*)d_in[8];
  const float* eeb2  = (const float*)d_in[9];
  const float* ecW1  = (const float*)d_in[10];
  const float* ecb1  = (const float*)d_in[11];
  const float* ecW2  = (const float*)d_in[12];
  const float* ecb2  = (const float*)d_in[13];
  const float* fW1   = (const float*)d_in[14];
  const float* fb1   = (const float*)d_in[15];
  const float* fW2   = (const float*)d_in[16];
  const float* fb2   = (const float*)d_in[17];
  const float* ln1   = (const float*)d_in[18];
  const float* ln2   = (const float*)d_in[19];
  const float* ln2b  = (const float*)d_in[20];
  const float* gW1   = (const float*)d_in[21];
  const float* gb1   = (const float*)d_in[22];
  const float* gW2   = (const float*)d_in[23];
  const float* gb2   = (const float*)d_in[24];
  const float* gW3   = (const float*)d_in[25];
  const float* gb3   = (const float*)d_in[26];
  const int* atype = (const int*)d_in[27];
  const int* ei    = (const int*)d_in[28];
  const int* etr   = (const int*)d_in[29];
  const int* etp   = (const int*)d_in[30];
  (void)etr; (void)etp;

  float* out = (float*)d_out;
  char* ws = (char*)d_ws;
  bf16_t* WT     = (bf16_t*)(ws);
  bf16_t* h16    = (bf16_t*)(ws + WSOFF_H16);
  bf16_t* hl     = (bf16_t*)(ws + WSOFF_HL);
  bf16_t* agg    = (bf16_t*)(ws + WSOFF_AGG);
  bf16_t* eattr  = (bf16_t*)(ws + WSOFF_EATTR);
  bf16_t* wfoldT = (bf16_t*)(ws + WSOFF_AGG);                  // transient, pre-conv
  float*  bfold  = (float*)(ws + WSOFF_AGG + AGGOFF_BFOLD);    // transient
  int*    perm   = (int*)(ws + WSOFF_AGG + AGGOFF_PERM);       // transient

  // fused setup: transpose + fold + foldb + node + prep + out-index-copy
  k_setup<<<9459, 256, 0, stream>>>(eeW2, ecW1, ecW2, fW1, fW2, ln1, ln2, gW1, gW2, WT,
                                    bemb, eeb2, ecb1, wfoldT, bfold, perm,
                                    rfeat, pfeat, emb, Wf, atype, h16, ei, out);
  k_edge_attr<<<1876, 512, 0, stream>>>(pos, ei, eeW1, eeb1, ecb2,
                                        wfoldT, bfold, perm, WT, eattr, out);
  k_lin1<<<157, 256, 0, stream>>>(h16, WT + OFF_LN1T, hl);
  for (int l = 0; l < 4; ++l) {
    k_msg<<<1000, 512, 0, stream>>>(eattr, hl,
                                    WT + OFF_FW1T + l * 65536, WT + OFF_FW2T + l * 65536,
                                    fb1 + l * 256, fb2 + l * 256, agg);
    k_updlin<<<157, 256, 0, stream>>>(agg, WT + OFF_LN2T + l * 65536, ln2b + l * 256,
                                      h16, WT + OFF_LN1T + (l + 1 < 4 ? l + 1 : 0) * 65536,
                                      hl, l < 3 ? 1 : 0);
  }
  k_head<<<EE / 64, 512, 0, stream>>>(h16, eattr, ei, gb1, gb2, gW3, gb3, WT, out);
}

// Round 11
// 611.252 us; speedup vs baseline: 1.2718x; 1.1793x over previous
//
#include <hip/hip_runtime.h>

#define NN 5000
#define EE 120000

typedef __bf16 bf16_t;
typedef __bf16 bf16x8 __attribute__((ext_vector_type(8)));
typedef float f32x4 __attribute__((ext_vector_type(4)));

// W^T offsets (elements) inside ws — all matrices stored FRAGMENT-PACKED:
// WTp[(kc*NCOL + col)*8 + j] = W[kc*8+j][col]   (kc = k>>3, j = k&7)
#define OFF_EEW2T 0
#define OFF_ECW1T 65536
#define OFF_ECW2T 196608
#define OFF_FW1T  262144
#define OFF_FW2T  524288
#define OFF_LN1T  786432
#define OFF_LN2T  1048576
#define OFF_GW1T  1310720
#define OFF_GW2T  1441792

// ws byte offsets (total 72,069,120 B — proven available)
#define WSOFF_H16   2949120
#define WSOFF_HL    5509120
#define WSOFF_AGG   8069120
#define WSOFF_EATTR 10629120
// transient region inside AGG (free until k_msg runs)
#define AGGOFF_BFOLD 524288
#define AGGOFF_PERM  528384

// edge-class metadata (within-molecule): order [d1, d2, d3, d>=4]
__device__ __constant__ int C_CNT[4] = {48, 46, 44, 462};
__device__ __constant__ int C_OFF[4] = {0, 48, 94, 138};

// XOR-swizzled [rows x 256] bf16 tile: 16B chunks permuted by row, conflict-free
__device__ __forceinline__ int swz(int r, int c) {
  return r * 256 + ((((c >> 3) ^ (r & 7)) << 3) | (c & 7));
}

__device__ __forceinline__ float silu_f(float x) { return x / (1.f + __expf(-x)); }
// fast shifted-softplus: native v_exp/v_log; |x| is O(1) here
__device__ __forceinline__ float ssp_f(float x) {
  return __logf(1.f + __expf(x)) - 0.6931472f;
}

// async global->LDS 16B copy: LDS dest = uniform base + lane*16 (HW),
// global source is per-lane (pre-swizzled to match the swizzled read layout)
__device__ __forceinline__ void async16(bf16_t* lds, const bf16_t* g) {
  __builtin_amdgcn_global_load_lds(
      (__attribute__((address_space(1))) const void*)g,
      (__attribute__((address_space(3))) void*)lds, 16, 0, 0);
}

// dst-major storage index for edge e (eattr is stored permuted):
// e = m*600 + i*24 + q, j = q + (q>=i)  ->  p = m*600 + j*24 + (i>j ? i-1 : i)
__device__ __forceinline__ int eperm(int e) {
  int m = e / 600, eloc = e - m * 600;
  int i = eloc / 24, q = eloc - i * 24;
  int j = q + (q >= i);
  return m * 600 + j * 24 + i - (i > j);
}

__device__ __forceinline__ bf16x8 zero8() {
  bf16x8 v;
#pragma unroll
  for (int q = 0; q < 8; ++q) v[q] = (__bf16)0.f;
  return v;
}

template<int RT, int NT>
__device__ __forceinline__ void zacc(f32x4 (&acc)[RT][NT]) {
#pragma unroll
  for (int i = 0; i < RT; ++i)
#pragma unroll
    for (int j = 0; j < NT; ++j) {
      f32x4 z = {0.f, 0.f, 0.f, 0.f};
      acc[i][j] = z;
    }
}

// A: LDS swizzled tile, rows rt*16+l15, k chunks ks*32+quad*8
// WT: fragment-packed global W^T: frag(kc,col) at WT+(kc*ncol+col)*8.
// Per B-load instruction: 4 quads x 256B contiguous (vs 16x64B with row-major W^T).
template<int RT, int NT, int KS>
__device__ __forceinline__ void gemm_lds(const bf16_t* __restrict__ A,
                                         const bf16_t* __restrict__ WT, int ncol,
                                         int colBase, f32x4 (&acc)[RT][NT], int lane) {
  const int l15 = lane & 15, quad = lane >> 4;
#pragma unroll
  for (int ks = 0; ks < KS; ++ks) {
    const int kc = ks * 4 + quad;
    bf16x8 a[RT];
#pragma unroll
    for (int rt = 0; rt < RT; ++rt) {
      int r = rt * 16 + l15;
      a[rt] = *(const bf16x8*)(A + r * 256 + ((kc ^ (r & 7)) << 3));
    }
#pragma unroll
    for (int nt = 0; nt < NT; ++nt) {
      const bf16x8 b = *(const bf16x8*)(WT + ((size_t)kc * ncol + colBase + nt * 16 + l15) * 8);
#pragma unroll
      for (int rt = 0; rt < RT; ++rt)
        acc[rt][nt] = __builtin_amdgcn_mfma_f32_16x16x32_bf16(a[rt], b, acc[rt][nt], 0, 0, 0);
    }
  }
}

// -------- fused setup: transpose ∪ fold ∪ foldb ∪ node ∪ prep ∪ out-copy --------
// grid partition (flat blockIdx.x, 256 threads):
//   [0,4992)            weight repack (1,277,952 elems, fragment-packed layout)
//   [4992,6016)         k_fold (p = b>>8, k = b&255)
//   [6016,6020)         k_foldb (p = b)
//   [6020,8520)         node embedding (2 nodes / block)
//   [8520,8521)         perm builder
//   [8521,9459)         out[EE..3EE] = float(ei)  (240,000 elems)
__global__ __launch_bounds__(256) void k_setup(
    const float* eeW2, const float* ecW1, const float* ecW2,
    const float* fW1, const float* fW2, const float* ln1, const float* ln2,
    const float* gW1, const float* gW2, bf16_t* WT,
    const float* bemb, const float* eeb2, const float* ecb1,
    bf16_t* wfoldT, float* bfold, int* perm,
    const float* r_feat, const float* p_feat, const float* emb, const float* Wf,
    const int* atype, bf16_t* h16, const int* ei, float* out) {
  __shared__ float rf[2][27], pf[2][27];
  const int tid = threadIdx.x;
  int b = blockIdx.x;
  if (b < 4992) {                       // ---- weight repack (fragment order) ----
    int g = b * 256 + tid;
    if (g < 1114112) {                  // segs 0..16: K=256, Nn=256
      int seg = g >> 16, idx = g & 65535;
      const float* src; int off;
      if (seg == 0)       { src = ecW2;                    off = OFF_ECW2T; }
      else if (seg <= 4)  { src = fW1 + (seg - 1) * 65536; off = OFF_FW1T + (seg - 1) * 65536; }
      else if (seg <= 8)  { src = fW2 + (seg - 5) * 65536; off = OFF_FW2T + (seg - 5) * 65536; }
      else if (seg <= 12) { src = ln1 + (seg - 9) * 65536; off = OFF_LN1T + (seg - 9) * 65536; }
      else                { src = ln2 + (seg - 13) * 65536; off = OFF_LN2T + (seg - 13) * 65536; }
      int j = idx & 7, n = (idx >> 3) & 255, kc = idx >> 11;
      int k = kc * 8 + j;
      WT[off + idx] = (bf16_t)src[k * 256 + n];
    } else if (g < 1245184) {           // seg 17: gW1, K=512, Nn=256
      int idx = g - 1114112;
      int j = idx & 7, n = (idx >> 3) & 255, kc = idx >> 11;   // kc 0..63
      int k = kc * 8 + j;
      WT[OFF_GW1T + idx] = (bf16_t)gW1[k * 256 + n];
    } else if (g < 1277952) {           // seg 18: gW2, K=256, Nn=128
      int idx = g - 1245184;
      int j = idx & 7, n = (idx >> 3) & 127, kc = idx >> 10;   // kc 0..31
      int k = kc * 8 + j;
      WT[OFF_GW2T + idx] = (bf16_t)gW2[k * 128 + n];
    }
    return;
  }
  b -= 4992;
  if (b < 1024) {                       // ---- k_fold (fragment-packed output) ----
    const int p = b >> 8, k = b & 255, n = tid;
    const int TR[4] = {1, 2, 3, 0}, TP[4] = {3, 2, 1, 0};
    const float* br = bemb + TR[p] * 256;
    const float* bp = bemb + TP[p] * 256;
    float acc = 0.f;
    for (int m = 0; m < 256; ++m) {
      float wc = br[m] * ecW1[m * 256 + n] + bp[m] * ecW1[(256 + m) * 256 + n];
      acc += eeW2[k * 256 + m] * wc;
    }
    wfoldT[p * 65536 + (((k >> 3) * 256 + n) << 3) + (k & 7)] = (bf16_t)acc;
    return;
  }
  b -= 1024;
  if (b < 4) {                          // ---- k_foldb ----
    const int p = b, n = tid;
    const int TR[4] = {1, 2, 3, 0}, TP[4] = {3, 2, 1, 0};
    const float* br = bemb + TR[p] * 256;
    const float* bp = bemb + TP[p] * 256;
    float acc = ecb1[n];
    for (int m = 0; m < 256; ++m) {
      float wc = br[m] * ecW1[m * 256 + n] + bp[m] * ecW1[(256 + m) * 256 + n];
      acc += eeb2[m] * wc;
    }
    bfold[p * 256 + n] = acc;
    return;
  }
  b -= 4;
  if (b < 2500) {                       // ---- node embedding, 2 nodes/block ----
    int half = tid >> 7, t = tid & 127;
    int n = b * 2 + half;
    if (t < 27) { rf[half][t] = r_feat[n * 27 + t]; pf[half][t] = p_feat[n * 27 + t]; }
    __syncthreads();
    float fr = 0.f, fp = 0.f;
#pragma unroll
    for (int k = 0; k < 27; ++k) {
      float w = Wf[k * 128 + t];
      fr += rf[half][k] * w; fp += pf[half][k] * w;
    }
    int at = atype[n];
    size_t base = (size_t)n * 256;
    h16[base + t] = (bf16_t)(emb[at * 128 + t] + fr);
    h16[base + 128 + t] = (bf16_t)(fp - fr);
    return;
  }
  b -= 2500;
  if (b < 1) {                          // ---- perm builder ----
    for (int e = tid; e < 600; e += 256) {
      int i = e / 24, q = e % 24;
      int j = q + (q >= i ? 1 : 0);
      int d = (i > j) ? (i - j) : (j - i);
      int cls = (d <= 3) ? (d - 1) : 3;
      int rank = 0;
      for (int e2 = 0; e2 < e; ++e2) {
        int i2 = e2 / 24, q2 = e2 % 24;
        int j2 = q2 + (q2 >= i2 ? 1 : 0);
        int d2 = (i2 > j2) ? (i2 - j2) : (j2 - i2);
        int c2 = (d2 <= 3) ? (d2 - 1) : 3;
        rank += (c2 == cls);
      }
      perm[C_OFF[cls] + rank] = e;
    }
    return;
  }
  b -= 1;
  {                                     // ---- out[EE..3EE] = float(ei) ----
    int idx = b * 256 + tid;
    if (idx < 2 * EE) out[EE + idx] = (float)ei[idx];
  }
}

// ------- fused edge embedding (proven r5/r8 config): 8-wave split, 64-row tile -------
// (512,6): 3 blocks/CU — measured optimum. (512,8) tripled FETCH via L2 thrash (r9).
__global__ __launch_bounds__(512, 6) void k_edge_attr(
    const float* __restrict__ pos, const int* __restrict__ ei,
    const float* __restrict__ eeW1, const float* __restrict__ eeb1,
    const float* __restrict__ ecb2,
    const bf16_t* __restrict__ wfoldT, const float* __restrict__ bfold,
    const int* __restrict__ perm,
    const bf16_t* __restrict__ WT, bf16_t* __restrict__ eattr, float* out) {
  __shared__ bf16_t B0[64 * 256];
  __shared__ float sW1f[256], sB1f[256];
  __shared__ int sE[64], sP[64];
  const int tid = threadIdx.x, lane = tid & 63, wave = tid >> 6;
  const int l15 = lane & 15, quad = lane >> 4;
  const int b = blockIdx.x;
  int cls, base;
  if (b < 150)      { cls = 0; base = b; }
  else if (b < 294) { cls = 1; base = b - 150; }
  else if (b < 432) { cls = 2; base = b - 294; }
  else              { cls = 3; base = b - 432; }
  const int cnt = C_CNT[cls], off = C_OFF[cls];

  if (tid < 256) { sW1f[tid] = eeW1[tid]; sB1f[tid] = eeb1[tid]; }
  if (tid < 64) {
    int slot = base * 64 + tid;
    int e = -1, p = 0;
    if (slot < cnt * 200) {
      int m = slot / cnt;
      int rr = slot - m * cnt;
      int eloc = perm[off + rr];
      e = m * 600 + eloc;
      p = eperm(e);
    }
    sE[tid] = e;
    sP[tid] = p;
  }
  __syncthreads();
  {
    int r = tid >> 3, cb = (tid & 7) * 32;
    int e = sE[r];
    float dd = 0.f;
    if (e >= 0) {
      int s = ei[e], dn = ei[EE + e];
      float d0 = pos[dn * 3 + 0] - pos[s * 3 + 0];
      float d1 = pos[dn * 3 + 1] - pos[s * 3 + 1];
      float d2 = pos[dn * 3 + 2] - pos[s * 3 + 2];
      dd = sqrtf(d0 * d0 + d1 * d1 + d2 * d2);
      if ((tid & 7) == 0) out[3 * EE + e] = dd;
    }
#pragma unroll
    for (int g = 0; g < 4; ++g) {
      int c0 = cb + g * 8;
      bf16x8 v;
#pragma unroll
      for (int q = 0; q < 8; ++q)
        v[q] = (bf16_t)silu_f(dd * sW1f[c0 + q] + sB1f[c0 + q]);
      *(bf16x8*)(B0 + swz(r, c0)) = v;
    }
  }
  __syncthreads();
  f32x4 acc[4][2];
  zacc(acc);
  gemm_lds<4, 2, 8>(B0, wfoldT + cls * 65536, 256, wave * 32, acc, lane);
  __syncthreads();
  {
    const float* bf = bfold + cls * 256;
    float bv[2];
#pragma unroll
    for (int nt = 0; nt < 2; ++nt) bv[nt] = bf[wave * 32 + nt * 16 + l15];
#pragma unroll
    for (int rt = 0; rt < 4; ++rt)
#pragma unroll
      for (int reg = 0; reg < 4; ++reg) {
        int r = rt * 16 + quad * 4 + reg;
#pragma unroll
        for (int nt = 0; nt < 2; ++nt) {
          int col = wave * 32 + nt * 16 + l15;
          B0[swz(r, col)] = (bf16_t)silu_f(acc[rt][nt][reg] + bv[nt]);
        }
      }
  }
  __syncthreads();
  zacc(acc);
  gemm_lds<4, 2, 8>(B0, WT + OFF_ECW2T, 256, wave * 32, acc, lane);
#pragma unroll
  for (int rt = 0; rt < 4; ++rt)
#pragma unroll
    for (int reg = 0; reg < 4; ++reg) {
      int r = rt * 16 + quad * 4 + reg;
      if (sE[r] >= 0) {
        int p = sP[r];
#pragma unroll
        for (int nt = 0; nt < 2; ++nt) {
          int col = wave * 32 + nt * 16 + l15;
          eattr[(size_t)p * 256 + col] = (bf16_t)(acc[rt][nt][reg] + ecb2[col]);
        }
      }
    }
}

// ------- message + segment-sum v11: 120-row tile (5 dst/block), grid 1000 -------
__global__ __launch_bounds__(512, 4) void k_msg(
    const bf16_t* __restrict__ eattr, const bf16_t* __restrict__ hl_g,
    const bf16_t* __restrict__ fW1T, const bf16_t* __restrict__ fW2T,
    const float* __restrict__ fb1, const float* __restrict__ fb2,
    bf16_t* __restrict__ agg) {
  __shared__ bf16_t buf[128 * 256];    // 64 KB
  __shared__ bf16_t hlb[26 * 264];     // 13.7 KB; row 25 = zeros
  __shared__ int sIdx[128];
  const int tid = threadIdx.x, lane = tid & 63, wave = tid >> 6;
  const int l15 = lane & 15, quad = lane >> 4;
  const int bid = blockIdx.x, m = bid / 5, p = bid % 5;
  const int j0 = p * 5;                // 5 dst nodes: j0..j0+4 (25 = 5*5 exact)
  const int pBase = m * 600 + j0 * 24; // contiguous 120 rows in dst-major eattr

  // async-stage 128 rows (120 valid + 8 dummy clamped to rows 0-7; gate 0)
  for (int it = wave; it < 64; it += 8) {
    int C = it * 64 + lane;            // chunk id 0..4095
    int r = C >> 5, kcs = C & 31;
    int rv = (r < 120) ? r : (r - 120);
    async16(buf + it * 512,
            eattr + (size_t)(pBase + rv) * 256 + ((kcs ^ (r & 7)) << 3));
  }
  // stage molecule's 25 hl rows + zero row 25
  for (int task = tid; task < 26 * 32; task += 512) {
    int i = task >> 5, kc = task & 31;
    bf16x8 v = (i < 25) ? *(const bf16x8*)(hl_g + (size_t)(m * 25 + i) * 256 + kc * 8)
                        : zero8();
    *(bf16x8*)(hlb + i * 264 + kc * 8) = v;
  }
  // precompute hlb row index per tile row
  if (tid < 128) {
    int r = tid;
    if (r < 120) {
      int g = r / 24, rr = r - g * 24, j = j0 + g;
      sIdx[r] = rr + (rr >= j);
    } else {
      sIdx[r] = 25;                    // zero gate for dummy rows
    }
  }
  __syncthreads();
  f32x4 acc[8][2];
  zacc(acc);
  gemm_lds<8, 2, 8>(buf, fW1T, 256, wave * 32, acc, lane);
  __syncthreads();
  {
    float b1[2];
#pragma unroll
    for (int nt = 0; nt < 2; ++nt) b1[nt] = fb1[wave * 32 + nt * 16 + l15];
#pragma unroll
    for (int rt = 0; rt < 8; ++rt)
#pragma unroll
      for (int reg = 0; reg < 4; ++reg) {
        int r = rt * 16 + quad * 4 + reg;
#pragma unroll
        for (int nt = 0; nt < 2; ++nt) {
          int c = wave * 32 + nt * 16 + l15;
          buf[swz(r, c)] = (bf16_t)ssp_f(acc[rt][nt][reg] + b1[nt]);
        }
      }
  }
  __syncthreads();
  zacc(acc);
  gemm_lds<8, 2, 8>(buf, fW2T, 256, wave * 32, acc, lane);
  // gated reduce into 5 dst buckets (compile-time bucket selection per rt)
  float s[5][2];
#pragma unroll
  for (int g = 0; g < 5; ++g) { s[g][0] = 0.f; s[g][1] = 0.f; }
#pragma unroll
  for (int nt = 0; nt < 2; ++nt) {
    int c = wave * 32 + nt * 16 + l15;
    float fb2c = fb2[c];
#pragma unroll
    for (int rt = 0; rt < 8; ++rt) {
      const int g0 = (rt * 16) / 24;           // compile-time
      const int bnd = (g0 + 1) * 24;
      const int g1 = (g0 < 4) ? (g0 + 1) : 4;  // dummy rows fold into bucket 4
#pragma unroll
      for (int reg = 0; reg < 4; ++reg) {
        int r = rt * 16 + quad * 4 + reg;
        float contrib = (acc[rt][nt][reg] + fb2c) * (float)hlb[sIdx[r] * 264 + c];
        if (r < bnd) s[g0][nt] += contrib; else s[g1][nt] += contrib;
      }
    }
  }
#pragma unroll
  for (int g = 0; g < 5; ++g)
#pragma unroll
    for (int nt = 0; nt < 2; ++nt) {
      float v = s[g][nt];
      v += __shfl_xor(v, 16);
      v += __shfl_xor(v, 32);
      s[g][nt] = v;
    }
  if (quad == 0) {
#pragma unroll
    for (int g = 0; g < 5; ++g)
#pragma unroll
      for (int nt = 0; nt < 2; ++nt) {
        int c = wave * 32 + nt * 16 + l15;
        agg[(size_t)(m * 25 + j0 + g) * 256 + c] = (bf16_t)s[g][nt];
      }
  }
}

// -------- fused: h += ssp(agg @ lin2 + b); optionally hl = h @ lin1 --------
// 32 nodes/block (grid 157): halves weight refetch vs 16-node version
__global__ __launch_bounds__(256) void k_updlin(
    const bf16_t* __restrict__ agg, const bf16_t* __restrict__ lin2T,
    const float* __restrict__ lin2b, bf16_t* h16,
    const bf16_t* __restrict__ lin1T, bf16_t* __restrict__ hl, int do_lin1) {
  __shared__ bf16_t buf[32 * 256];
  __shared__ bf16_t hbuf[32 * 256];
  const int tid = threadIdx.x, lane = tid & 63, wave = tid >> 6;
  const int l15 = lane & 15, quad = lane >> 4;
  const int row0 = blockIdx.x * 32;
  // async-stage agg + h rows (pad rows clamp to node NN-1; outputs guarded)
  for (int it = wave; it < 16; it += 4) {
    int C = it * 64 + lane;
    int r = C >> 5, kcs = C & 31;
    int node = row0 + r;
    size_t rowoff = (size_t)(node < NN ? node : NN - 1) * 256 + ((kcs ^ (r & 7)) << 3);
    async16(buf + it * 512, agg + rowoff);
    async16(hbuf + it * 512, h16 + rowoff);
  }
  __syncthreads();
  f32x4 acc[2][4];
  zacc(acc);
  gemm_lds<2, 4, 8>(buf, lin2T, 256, wave * 64, acc, lane);
  {
    float b2[4];
#pragma unroll
    for (int nt = 0; nt < 4; ++nt) b2[nt] = lin2b[wave * 64 + nt * 16 + l15];
#pragma unroll
    for (int rt = 0; rt < 2; ++rt)
#pragma unroll
      for (int reg = 0; reg < 4; ++reg) {
        int r = rt * 16 + quad * 4 + reg, node = row0 + r;
#pragma unroll
        for (int nt = 0; nt < 4; ++nt) {
          int c = wave * 64 + nt * 16 + l15;
          int idx = swz(r, c);
          float hn = (float)hbuf[idx] + ssp_f(acc[rt][nt][reg] + b2[nt]);
          bf16_t hb = (bf16_t)hn;
          hbuf[idx] = hb;
          if (node < NN) h16[(size_t)node * 256 + c] = hb;
        }
      }
  }
  if (!do_lin1) return;
  __syncthreads();
  f32x4 acc2[2][4];
  zacc(acc2);
  gemm_lds<2, 4, 8>(hbuf, lin1T, 256, wave * 64, acc2, lane);
#pragma unroll
  for (int rt = 0; rt < 2; ++rt)
#pragma unroll
    for (int reg = 0; reg < 4; ++reg) {
      int r = rt * 16 + quad * 4 + reg, node = row0 + r;
      if (node < NN) {
#pragma unroll
        for (int nt = 0; nt < 4; ++nt) {
          int c = wave * 64 + nt * 16 + l15;
          hl[(size_t)node * 256 + c] = (bf16_t)acc2[rt][nt][reg];
        }
      }
    }
}

// ---------------- hl = h @ lin1 (no bias), initial ----------------
__global__ __launch_bounds__(256) void k_lin1(
    const bf16_t* __restrict__ h16, const bf16_t* __restrict__ lin1T,
    bf16_t* __restrict__ hl) {
  __shared__ bf16_t buf[32 * 256];
  const int tid = threadIdx.x, lane = tid & 63, wave = tid >> 6;
  const int l15 = lane & 15, quad = lane >> 4;
  const int row0 = blockIdx.x * 32;
  for (int it = wave; it < 16; it += 4) {
    int C = it * 64 + lane;
    int r = C >> 5, kcs = C & 31;
    int node = row0 + r;
    async16(buf + it * 512,
            h16 + (size_t)(node < NN ? node : NN - 1) * 256 + ((kcs ^ (r & 7)) << 3));
  }
  __syncthreads();
  f32x4 acc[2][4];
  zacc(acc);
  gemm_lds<2, 4, 8>(buf, lin1T, 256, wave * 64, acc, lane);
#pragma unroll
  for (int rt = 0; rt < 2; ++rt)
#pragma unroll
    for (int reg = 0; reg < 4; ++reg) {
      int r = rt * 16 + quad * 4 + reg, node = row0 + r;
      if (node < NN) {
#pragma unroll
        for (int nt = 0; nt < 4; ++nt) {
          int c = wave * 64 + nt * 16 + l15;
          hl[(size_t)node * 256 + c] = (bf16_t)acc[rt][nt][reg];
        }
      }
    }
}

// ------- output head: dual-buffer, eattr async under GEMM1a -------
__global__ __launch_bounds__(512, 4) void k_head(
    const bf16_t* __restrict__ h16, const bf16_t* __restrict__ eattr, const int* ei,
    const float* gb1, const float* gb2, const float* gW3, const float* gb3,
    const bf16_t* WT, float* out) {
  __shared__ bf16_t B0[64 * 256];      // h_src * h_dst  (K 0-255)
  __shared__ bf16_t B1[64 * 256];      // eattr          (K 256-511)
  __shared__ int sP[64];
  const int tid = threadIdx.x, lane = tid & 63, wave = tid >> 6;
  const int l15 = lane & 15, quad = lane >> 4;
  const int eBase = blockIdx.x * 64;
  const int colB = wave * 32;

  if (tid < 64) sP[tid] = eperm(eBase + tid);
  for (int task = tid; task < 64 * 32; task += 512) {
    int r = task >> 5, kc = task & 31;
    int e = eBase + r, s = ei[e], dn = ei[EE + e];
    bf16x8 a = *(const bf16x8*)(h16 + (size_t)s * 256 + kc * 8);
    bf16x8 b = *(const bf16x8*)(h16 + (size_t)dn * 256 + kc * 8);
    bf16x8 v;
#pragma unroll
    for (int q = 0; q < 8; ++q) v[q] = (bf16_t)((float)a[q] * (float)b[q]);
    *(bf16x8*)(B0 + r * 256 + ((kc ^ (r & 7)) << 3)) = v;
  }
  __syncthreads();
  // issue eattr async-stage into B1 NOW; GEMM1a's 128 MFMA hide the latency,
  // and the next barrier's vmcnt drain guarantees completion before G1b.
  for (int it = wave; it < 32; it += 8) {
    int C = it * 64 + lane;
    int r = C >> 5, kcs = C & 31;
    async16(B1 + it * 512,
            eattr + (size_t)sP[r] * 256 + ((kcs ^ (r & 7)) << 3));
  }
  f32x4 acc1[4][2];
  zacc(acc1);
  gemm_lds<4, 2, 8>(B0, WT + OFF_GW1T, 256, colB, acc1, lane);
  __syncthreads();
  // gW1 K-rows 256..511 = fragment rows kc 32..63 -> base offset 32*256*8 = 65536
  gemm_lds<4, 2, 8>(B1, WT + OFF_GW1T + 65536, 256, colB, acc1, lane);
  // no barrier: epilogue writes B0 only; G1b reads B1 only.
  {
    float b1v[2];
#pragma unroll
    for (int nt = 0; nt < 2; ++nt) b1v[nt] = gb1[colB + nt * 16 + l15];
#pragma unroll
    for (int rt = 0; rt < 4; ++rt)
#pragma unroll
      for (int reg = 0; reg < 4; ++reg) {
        int r = rt * 16 + quad * 4 + reg;
#pragma unroll
        for (int nt = 0; nt < 2; ++nt) {
          int c = colB + nt * 16 + l15;
          B0[swz(r, c)] = (bf16_t)silu_f(acc1[rt][nt][reg] + b1v[nt]);
        }
      }
  }
  __syncthreads();
  f32x4 acc2[4][1];
  zacc(acc2);
  gemm_lds<4, 1, 8>(B0, WT + OFF_GW2T, 128, wave * 16, acc2, lane);
  __syncthreads();
  {
    float b2v = gb2[wave * 16 + l15];
#pragma unroll
    for (int rt = 0; rt < 4; ++rt)
#pragma unroll
      for (int reg = 0; reg < 4; ++reg) {
        int r = rt * 16 + quad * 4 + reg;
        int c = wave * 16 + l15;
        B0[swz(r, c)] = (bf16_t)silu_f(acc2[rt][0][reg] + b2v);
      }
  }
  __syncthreads();
  {
    // vectorized final dot over 128 cols: 2 x ds_read_b128 + 4 x f32x4 per thread
    int r = tid >> 3, part = tid & 7;
    float s = 0.f;
#pragma unroll
    for (int g = 0; g < 2; ++g) {
      int chunk = part * 2 + g;                       // col chunk (c = chunk*8+q)
      const bf16x8 v = *(const bf16x8*)(B0 + r * 256 + ((chunk ^ (r & 7)) << 3));
      const f32x4 w0 = *(const f32x4*)(gW3 + part * 16 + g * 8);
      const f32x4 w1 = *(const f32x4*)(gW3 + part * 16 + g * 8 + 4);
#pragma unroll
      for (int q = 0; q < 4; ++q) s += (float)v[q] * w0[q];
#pragma unroll
      for (int q = 0; q < 4; ++q) s += (float)v[4 + q] * w1[q];
    }
    s += __shfl_xor(s, 1);
    s += __shfl_xor(s, 2);
    s += __shfl_xor(s, 4);
    if (part == 0) out[eBase + r] = s + gb3[0];
  }
}

extern "C" void kernel_launch(void* const* d_in, const int* in_sizes, int n_in,
                              void* d_out, int out_size, void* d_ws, size_t ws_size,
                              hipStream_t stream) {
  const float* pos   = (const float*)d_in[0];
  const float* rfeat = (const float*)d_in[1];
  const float* pfeat = (const float*)d_in[2];
  const float* emb   = (const float*)d_in[3];
  const float* Wf    = (const float*)d_in[4];
  const float* bemb  = (const float*)d_in[5];
  const float* eeW1  = (const float*)d_in[6];
  const float* eeb1  = (const float*)d_in[7];
  const float* eeW2  = (const float*)d_in[8];
  const float* eeb2  = (const float*)d_in[9];
  const float* ecW1  = (const float*)d_in[10];
  const float* ecb1  = (const float*)d_in[11];
  const float* ecW2  = (const float*)d_in[12];
  const float* ecb2  = (const float*)d_in[13];
  const float* fW1   = (const float*)d_in[14];
  const float* fb1   = (const float*)d_in[15];
  const float* fW2   = (const float*)d_in[16];
  const float* fb2   = (const float*)d_in[17];
  const float* ln1   = (const float*)d_in[18];
  const float* ln2   = (const float*)d_in[19];
  const float* ln2b  = (const float*)d_in[20];
  const float* gW1   = (const float*)d_in[21];
  const float* gb1   = (const float*)d_in[22];
  const float* gW2   = (const float*)d_in[23];
  const float* gb2   = (const float*)d_in[24];
  const float* gW3   = (const float*)d_in[25];
  const float* gb3   = (const float*)d_in[26];
  const int* atype = (const int*)d_in[27];
  const int* ei    = (const int*)d_in[28];
  const int* etr   = (const int*)d_in[29];
  const int* etp   = (const int*)d_in[30];
  (void)etr; (void)etp;

  float* out = (float*)d_out;
  char* ws = (char*)d_ws;
  bf16_t* WT     = (bf16_t*)(ws);
  bf16_t* h16    = (bf16_t*)(ws + WSOFF_H16);
  bf16_t* hl     = (bf16_t*)(ws + WSOFF_HL);
  bf16_t* agg    = (bf16_t*)(ws + WSOFF_AGG);
  bf16_t* eattr  = (bf16_t*)(ws + WSOFF_EATTR);
  bf16_t* wfoldT = (bf16_t*)(ws + WSOFF_AGG);                  // transient, pre-conv
  float*  bfold  = (float*)(ws + WSOFF_AGG + AGGOFF_BFOLD);    // transient
  int*    perm   = (int*)(ws + WSOFF_AGG + AGGOFF_PERM);       // transient

  // fused setup: repack + fold + foldb + node + prep + out-index-copy
  k_setup<<<9459, 256, 0, stream>>>(eeW2, ecW1, ecW2, fW1, fW2, ln1, ln2, gW1, gW2, WT,
                                    bemb, eeb2, ecb1, wfoldT, bfold, perm,
                                    rfeat, pfeat, emb, Wf, atype, h16, ei, out);
  k_edge_attr<<<1876, 512, 0, stream>>>(pos, ei, eeW1, eeb1, ecb2,
                                        wfoldT, bfold, perm, WT, eattr, out);
  k_lin1<<<157, 256, 0, stream>>>(h16, WT + OFF_LN1T, hl);
  for (int l = 0; l < 4; ++l) {
    k_msg<<<1000, 512, 0, stream>>>(eattr, hl,
                                    WT + OFF_FW1T + l * 65536, WT + OFF_FW2T + l * 65536,
                                    fb1 + l * 256, fb2 + l * 256, agg);
    k_updlin<<<157, 256, 0, stream>>>(agg, WT + OFF_LN2T + l * 65536, ln2b + l * 256,
                                      h16, WT + OFF_LN1T + (l + 1 < 4 ? l + 1 : 0) * 65536,
                                      hl, l < 3 ? 1 : 0);
  }
  k_head<<<EE / 64, 512, 0, stream>>>(h16, eattr, ei, gb1, gb2, gW3, gb3, WT, out);
}

// Round 12
// 575.925 us; speedup vs baseline: 1.3498x; 1.0613x over previous
//
#include <hip/hip_runtime.h>

#define NN 5000
#define EE 120000

typedef __bf16 bf16_t;
typedef __bf16 bf16x8 __attribute__((ext_vector_type(8)));
typedef float f32x4 __attribute__((ext_vector_type(4)));

// W^T offsets (elements) inside ws — all matrices stored FRAGMENT-PACKED:
// WTp[(kc*NCOL + col)*8 + j] = W[kc*8+j][col]   (kc = k>>3, j = k&7)
#define OFF_EEW2T 0
#define OFF_ECW1T 65536
#define OFF_ECW2T 196608
#define OFF_FW1T  262144
#define OFF_FW2T  524288
#define OFF_LN1T  786432
#define OFF_LN2T  1048576
#define OFF_GW1T  1310720
#define OFF_GW2T  1441792

// ws byte offsets (total 72,069,120 B — proven available)
#define WSOFF_H16   2949120
#define WSOFF_HL    5509120
#define WSOFF_AGG   8069120
#define WSOFF_EATTR 10629120
// transient region inside AGG (free until k_msg runs)
#define AGGOFF_BFOLD 524288
#define AGGOFF_PERM  528384

// edge-class metadata (within-molecule): order [d1, d2, d3, d>=4]
__device__ __constant__ int C_CNT[4] = {48, 46, 44, 462};
__device__ __constant__ int C_OFF[4] = {0, 48, 94, 138};

// XOR-swizzled [rows x 256] bf16 tile: 16B chunks permuted by row, conflict-free
__device__ __forceinline__ int swz(int r, int c) {
  return r * 256 + ((((c >> 3) ^ (r & 7)) << 3) | (c & 7));
}

__device__ __forceinline__ float silu_f(float x) { return x / (1.f + __expf(-x)); }
// fast shifted-softplus: native v_exp/v_log; |x| is O(1) here
__device__ __forceinline__ float ssp_f(float x) {
  return __logf(1.f + __expf(x)) - 0.6931472f;
}

// async global->LDS 16B copy: LDS dest = uniform base + lane*16 (HW),
// global source is per-lane (pre-swizzled to match the swizzled read layout)
__device__ __forceinline__ void async16(bf16_t* lds, const bf16_t* g) {
  __builtin_amdgcn_global_load_lds(
      (__attribute__((address_space(1))) const void*)g,
      (__attribute__((address_space(3))) void*)lds, 16, 0, 0);
}

// dst-major storage index for edge e (eattr is stored permuted):
// e = m*600 + i*24 + q, j = q + (q>=i)  ->  p = m*600 + j*24 + (i>j ? i-1 : i)
__device__ __forceinline__ int eperm(int e) {
  int m = e / 600, eloc = e - m * 600;
  int i = eloc / 24, q = eloc - i * 24;
  int j = q + (q >= i);
  return m * 600 + j * 24 + i - (i > j);
}

__device__ __forceinline__ bf16x8 zero8() {
  bf16x8 v;
#pragma unroll
  for (int q = 0; q < 8; ++q) v[q] = (__bf16)0.f;
  return v;
}

template<int RT, int NT>
__device__ __forceinline__ void zacc(f32x4 (&acc)[RT][NT]) {
#pragma unroll
  for (int i = 0; i < RT; ++i)
#pragma unroll
    for (int j = 0; j < NT; ++j) {
      f32x4 z = {0.f, 0.f, 0.f, 0.f};
      acc[i][j] = z;
    }
}

// A: LDS swizzled tile, rows rt*16+l15, k chunks ks*32+quad*8
// WT: fragment-packed global W^T: frag(kc,col) at WT+(kc*ncol+col)*8.
// Per B-load instruction: 4 quads x 256B contiguous (vs 16x64B with row-major W^T).
template<int RT, int NT, int KS>
__device__ __forceinline__ void gemm_lds(const bf16_t* __restrict__ A,
                                         const bf16_t* __restrict__ WT, int ncol,
                                         int colBase, f32x4 (&acc)[RT][NT], int lane) {
  const int l15 = lane & 15, quad = lane >> 4;
#pragma unroll
  for (int ks = 0; ks < KS; ++ks) {
    const int kc = ks * 4 + quad;
    bf16x8 a[RT];
#pragma unroll
    for (int rt = 0; rt < RT; ++rt) {
      int r = rt * 16 + l15;
      a[rt] = *(const bf16x8*)(A + r * 256 + ((kc ^ (r & 7)) << 3));
    }
#pragma unroll
    for (int nt = 0; nt < NT; ++nt) {
      const bf16x8 b = *(const bf16x8*)(WT + ((size_t)kc * ncol + colBase + nt * 16 + l15) * 8);
#pragma unroll
      for (int rt = 0; rt < RT; ++rt)
        acc[rt][nt] = __builtin_amdgcn_mfma_f32_16x16x32_bf16(a[rt], b, acc[rt][nt], 0, 0, 0);
    }
  }
}

// -------- fused setup: fold ∪ foldb ∪ repack ∪ node ∪ prep ∪ out-copy --------
// grid partition (flat blockIdx.x, 256 threads). Fold blocks FIRST (long pole;
// short repack/node/copy blocks co-schedule and hide its latency):
//   [0,256)             k_fold, k-tiled x4 (p = b>>6, kq = b&63) — wc computed
//                       once per m, feeds 4 accumulators (ecW1 traffic /4)
//   [256,260)           k_foldb (p = b-256)
//   [260,5252)          weight repack (1,277,952 elems, fragment-packed layout)
//   [5252,7752)         node embedding (2 nodes / block)
//   [7752,7753)         perm builder
//   [7753,8691)         out[EE..3EE] = float(ei)  (240,000 elems)
__global__ __launch_bounds__(256) void k_setup(
    const float* eeW2, const float* ecW1, const float* ecW2,
    const float* fW1, const float* fW2, const float* ln1, const float* ln2,
    const float* gW1, const float* gW2, bf16_t* WT,
    const float* bemb, const float* eeb2, const float* ecb1,
    bf16_t* wfoldT, float* bfold, int* perm,
    const float* r_feat, const float* p_feat, const float* emb, const float* Wf,
    const int* atype, bf16_t* h16, const int* ei, float* out) {
  __shared__ float rf[2][27], pf[2][27];
  const int tid = threadIdx.x;
  int b = blockIdx.x;
  if (b < 256) {                        // ---- k_fold, 4 k per block ----
    const int p = b >> 6, kq = b & 63, n = tid;
    const int TR[4] = {1, 2, 3, 0}, TP[4] = {3, 2, 1, 0};
    const float* br = bemb + TR[p] * 256;
    const float* bp = bemb + TP[p] * 256;
    const float* w0 = eeW2 + (kq * 4 + 0) * 256;
    const float* w1 = eeW2 + (kq * 4 + 1) * 256;
    const float* w2 = eeW2 + (kq * 4 + 2) * 256;
    const float* w3 = eeW2 + (kq * 4 + 3) * 256;
    float a0 = 0.f, a1 = 0.f, a2 = 0.f, a3 = 0.f;
    for (int m = 0; m < 256; ++m) {
      float wc = br[m] * ecW1[m * 256 + n] + bp[m] * ecW1[(256 + m) * 256 + n];
      a0 += w0[m] * wc;
      a1 += w1[m] * wc;
      a2 += w2[m] * wc;
      a3 += w3[m] * wc;
    }
#pragma unroll
    for (int i = 0; i < 4; ++i) {
      int k = kq * 4 + i;
      float a = (i == 0) ? a0 : (i == 1) ? a1 : (i == 2) ? a2 : a3;
      wfoldT[p * 65536 + (((k >> 3) * 256 + n) << 3) + (k & 7)] = (bf16_t)a;
    }
    return;
  }
  b -= 256;
  if (b < 4) {                          // ---- k_foldb ----
    const int p = b, n = tid;
    const int TR[4] = {1, 2, 3, 0}, TP[4] = {3, 2, 1, 0};
    const float* br = bemb + TR[p] * 256;
    const float* bp = bemb + TP[p] * 256;
    float acc = ecb1[n];
    for (int m = 0; m < 256; ++m) {
      float wc = br[m] * ecW1[m * 256 + n] + bp[m] * ecW1[(256 + m) * 256 + n];
      acc += eeb2[m] * wc;
    }
    bfold[p * 256 + n] = acc;
    return;
  }
  b -= 4;
  if (b < 4992) {                       // ---- weight repack (fragment order) ----
    int g = b * 256 + tid;
    if (g < 1114112) {                  // segs 0..16: K=256, Nn=256
      int seg = g >> 16, idx = g & 65535;
      const float* src; int off;
      if (seg == 0)       { src = ecW2;                    off = OFF_ECW2T; }
      else if (seg <= 4)  { src = fW1 + (seg - 1) * 65536; off = OFF_FW1T + (seg - 1) * 65536; }
      else if (seg <= 8)  { src = fW2 + (seg - 5) * 65536; off = OFF_FW2T + (seg - 5) * 65536; }
      else if (seg <= 12) { src = ln1 + (seg - 9) * 65536; off = OFF_LN1T + (seg - 9) * 65536; }
      else                { src = ln2 + (seg - 13) * 65536; off = OFF_LN2T + (seg - 13) * 65536; }
      int j = idx & 7, n = (idx >> 3) & 255, kc = idx >> 11;
      int k = kc * 8 + j;
      WT[off + idx] = (bf16_t)src[k * 256 + n];
    } else if (g < 1245184) {           // seg 17: gW1, K=512, Nn=256
      int idx = g - 1114112;
      int j = idx & 7, n = (idx >> 3) & 255, kc = idx >> 11;   // kc 0..63
      int k = kc * 8 + j;
      WT[OFF_GW1T + idx] = (bf16_t)gW1[k * 256 + n];
    } else if (g < 1277952) {           // seg 18: gW2, K=256, Nn=128
      int idx = g - 1245184;
      int j = idx & 7, n = (idx >> 3) & 127, kc = idx >> 10;   // kc 0..31
      int k = kc * 8 + j;
      WT[OFF_GW2T + idx] = (bf16_t)gW2[k * 128 + n];
    }
    return;
  }
  b -= 4992;
  if (b < 2500) {                       // ---- node embedding, 2 nodes/block ----
    int half = tid >> 7, t = tid & 127;
    int n = b * 2 + half;
    if (t < 27) { rf[half][t] = r_feat[n * 27 + t]; pf[half][t] = p_feat[n * 27 + t]; }
    __syncthreads();
    float fr = 0.f, fp = 0.f;
#pragma unroll
    for (int k = 0; k < 27; ++k) {
      float w = Wf[k * 128 + t];
      fr += rf[half][k] * w; fp += pf[half][k] * w;
    }
    int at = atype[n];
    size_t base = (size_t)n * 256;
    h16[base + t] = (bf16_t)(emb[at * 128 + t] + fr);
    h16[base + 128 + t] = (bf16_t)(fp - fr);
    return;
  }
  b -= 2500;
  if (b < 1) {                          // ---- perm builder ----
    for (int e = tid; e < 600; e += 256) {
      int i = e / 24, q = e % 24;
      int j = q + (q >= i ? 1 : 0);
      int d = (i > j) ? (i - j) : (j - i);
      int cls = (d <= 3) ? (d - 1) : 3;
      int rank = 0;
      for (int e2 = 0; e2 < e; ++e2) {
        int i2 = e2 / 24, q2 = e2 % 24;
        int j2 = q2 + (q2 >= i2 ? 1 : 0);
        int d2 = (i2 > j2) ? (i2 - j2) : (j2 - i2);
        int c2 = (d2 <= 3) ? (d2 - 1) : 3;
        rank += (c2 == cls);
      }
      perm[C_OFF[cls] + rank] = e;
    }
    return;
  }
  b -= 1;
  {                                     // ---- out[EE..3EE] = float(ei) ----
    int idx = b * 256 + tid;
    if (idx < 2 * EE) out[EE + idx] = (float)ei[idx];
  }
}

// ------- fused edge embedding (proven r5/r8 config): 8-wave split, 64-row tile -------
// (512,6): 3 blocks/CU — measured optimum. (512,8) tripled FETCH via L2 thrash (r9).
__global__ __launch_bounds__(512, 6) void k_edge_attr(
    const float* __restrict__ pos, const int* __restrict__ ei,
    const float* __restrict__ eeW1, const float* __restrict__ eeb1,
    const float* __restrict__ ecb2,
    const bf16_t* __restrict__ wfoldT, const float* __restrict__ bfold,
    const int* __restrict__ perm,
    const bf16_t* __restrict__ WT, bf16_t* __restrict__ eattr, float* out) {
  __shared__ bf16_t B0[64 * 256];
  __shared__ float sW1f[256], sB1f[256];
  __shared__ int sE[64], sP[64];
  const int tid = threadIdx.x, lane = tid & 63, wave = tid >> 6;
  const int l15 = lane & 15, quad = lane >> 4;
  const int b = blockIdx.x;
  int cls, base;
  if (b < 150)      { cls = 0; base = b; }
  else if (b < 294) { cls = 1; base = b - 150; }
  else if (b < 432) { cls = 2; base = b - 294; }
  else              { cls = 3; base = b - 432; }
  const int cnt = C_CNT[cls], off = C_OFF[cls];

  if (tid < 256) { sW1f[tid] = eeW1[tid]; sB1f[tid] = eeb1[tid]; }
  if (tid < 64) {
    int slot = base * 64 + tid;
    int e = -1, p = 0;
    if (slot < cnt * 200) {
      int m = slot / cnt;
      int rr = slot - m * cnt;
      int eloc = perm[off + rr];
      e = m * 600 + eloc;
      p = eperm(e);
    }
    sE[tid] = e;
    sP[tid] = p;
  }
  __syncthreads();
  {
    int r = tid >> 3, cb = (tid & 7) * 32;
    int e = sE[r];
    float dd = 0.f;
    if (e >= 0) {
      int s = ei[e], dn = ei[EE + e];
      float d0 = pos[dn * 3 + 0] - pos[s * 3 + 0];
      float d1 = pos[dn * 3 + 1] - pos[s * 3 + 1];
      float d2 = pos[dn * 3 + 2] - pos[s * 3 + 2];
      dd = sqrtf(d0 * d0 + d1 * d1 + d2 * d2);
      if ((tid & 7) == 0) out[3 * EE + e] = dd;
    }
#pragma unroll
    for (int g = 0; g < 4; ++g) {
      int c0 = cb + g * 8;
      bf16x8 v;
#pragma unroll
      for (int q = 0; q < 8; ++q)
        v[q] = (bf16_t)silu_f(dd * sW1f[c0 + q] + sB1f[c0 + q]);
      *(bf16x8*)(B0 + swz(r, c0)) = v;
    }
  }
  __syncthreads();
  f32x4 acc[4][2];
  zacc(acc);
  gemm_lds<4, 2, 8>(B0, wfoldT + cls * 65536, 256, wave * 32, acc, lane);
  __syncthreads();
  {
    const float* bf = bfold + cls * 256;
    float bv[2];
#pragma unroll
    for (int nt = 0; nt < 2; ++nt) bv[nt] = bf[wave * 32 + nt * 16 + l15];
#pragma unroll
    for (int rt = 0; rt < 4; ++rt)
#pragma unroll
      for (int reg = 0; reg < 4; ++reg) {
        int r = rt * 16 + quad * 4 + reg;
#pragma unroll
        for (int nt = 0; nt < 2; ++nt) {
          int col = wave * 32 + nt * 16 + l15;
          B0[swz(r, col)] = (bf16_t)silu_f(acc[rt][nt][reg] + bv[nt]);
        }
      }
  }
  __syncthreads();
  zacc(acc);
  gemm_lds<4, 2, 8>(B0, WT + OFF_ECW2T, 256, wave * 32, acc, lane);
#pragma unroll
  for (int rt = 0; rt < 4; ++rt)
#pragma unroll
    for (int reg = 0; reg < 4; ++reg) {
      int r = rt * 16 + quad * 4 + reg;
      if (sE[r] >= 0) {
        int p = sP[r];
#pragma unroll
        for (int nt = 0; nt < 2; ++nt) {
          int col = wave * 32 + nt * 16 + l15;
          eattr[(size_t)p * 256 + col] = (bf16_t)(acc[rt][nt][reg] + ecb2[col]);
        }
      }
    }
}

// ------- message + segment-sum v11: 120-row tile (5 dst/block), grid 1000 -------
__global__ __launch_bounds__(512, 4) void k_msg(
    const bf16_t* __restrict__ eattr, const bf16_t* __restrict__ hl_g,
    const bf16_t* __restrict__ fW1T, const bf16_t* __restrict__ fW2T,
    const float* __restrict__ fb1, const float* __restrict__ fb2,
    bf16_t* __restrict__ agg) {
  __shared__ bf16_t buf[128 * 256];    // 64 KB
  __shared__ bf16_t hlb[26 * 264];     // 13.7 KB; row 25 = zeros
  __shared__ int sIdx[128];
  const int tid = threadIdx.x, lane = tid & 63, wave = tid >> 6;
  const int l15 = lane & 15, quad = lane >> 4;
  const int bid = blockIdx.x, m = bid / 5, p = bid % 5;
  const int j0 = p * 5;                // 5 dst nodes: j0..j0+4 (25 = 5*5 exact)
  const int pBase = m * 600 + j0 * 24; // contiguous 120 rows in dst-major eattr

  // async-stage 128 rows (120 valid + 8 dummy clamped to rows 0-7; gate 0)
  for (int it = wave; it < 64; it += 8) {
    int C = it * 64 + lane;            // chunk id 0..4095
    int r = C >> 5, kcs = C & 31;
    int rv = (r < 120) ? r : (r - 120);
    async16(buf + it * 512,
            eattr + (size_t)(pBase + rv) * 256 + ((kcs ^ (r & 7)) << 3));
  }
  // stage molecule's 25 hl rows + zero row 25
  for (int task = tid; task < 26 * 32; task += 512) {
    int i = task >> 5, kc = task & 31;
    bf16x8 v = (i < 25) ? *(const bf16x8*)(hl_g + (size_t)(m * 25 + i) * 256 + kc * 8)
                        : zero8();
    *(bf16x8*)(hlb + i * 264 + kc * 8) = v;
  }
  // precompute hlb row index per tile row
  if (tid < 128) {
    int r = tid;
    if (r < 120) {
      int g = r / 24, rr = r - g * 24, j = j0 + g;
      sIdx[r] = rr + (rr >= j);
    } else {
      sIdx[r] = 25;                    // zero gate for dummy rows
    }
  }
  __syncthreads();
  f32x4 acc[8][2];
  zacc(acc);
  gemm_lds<8, 2, 8>(buf, fW1T, 256, wave * 32, acc, lane);
  __syncthreads();
  {
    float b1[2];
#pragma unroll
    for (int nt = 0; nt < 2; ++nt) b1[nt] = fb1[wave * 32 + nt * 16 + l15];
#pragma unroll
    for (int rt = 0; rt < 8; ++rt)
#pragma unroll
      for (int reg = 0; reg < 4; ++reg) {
        int r = rt * 16 + quad * 4 + reg;
#pragma unroll
        for (int nt = 0; nt < 2; ++nt) {
          int c = wave * 32 + nt * 16 + l15;
          buf[swz(r, c)] = (bf16_t)ssp_f(acc[rt][nt][reg] + b1[nt]);
        }
      }
  }
  __syncthreads();
  zacc(acc);
  gemm_lds<8, 2, 8>(buf, fW2T, 256, wave * 32, acc, lane);
  // gated reduce into 5 dst buckets (compile-time bucket selection per rt)
  float s[5][2];
#pragma unroll
  for (int g = 0; g < 5; ++g) { s[g][0] = 0.f; s[g][1] = 0.f; }
#pragma unroll
  for (int nt = 0; nt < 2; ++nt) {
    int c = wave * 32 + nt * 16 + l15;
    float fb2c = fb2[c];
#pragma unroll
    for (int rt = 0; rt < 8; ++rt) {
      const int g0 = (rt * 16) / 24;           // compile-time
      const int bnd = (g0 + 1) * 24;
      const int g1 = (g0 < 4) ? (g0 + 1) : 4;  // dummy rows fold into bucket 4
#pragma unroll
      for (int reg = 0; reg < 4; ++reg) {
        int r = rt * 16 + quad * 4 + reg;
        float contrib = (acc[rt][nt][reg] + fb2c) * (float)hlb[sIdx[r] * 264 + c];
        if (r < bnd) s[g0][nt] += contrib; else s[g1][nt] += contrib;
      }
    }
  }
#pragma unroll
  for (int g = 0; g < 5; ++g)
#pragma unroll
    for (int nt = 0; nt < 2; ++nt) {
      float v = s[g][nt];
      v += __shfl_xor(v, 16);
      v += __shfl_xor(v, 32);
      s[g][nt] = v;
    }
  if (quad == 0) {
#pragma unroll
    for (int g = 0; g < 5; ++g)
#pragma unroll
      for (int nt = 0; nt < 2; ++nt) {
        int c = wave * 32 + nt * 16 + l15;
        agg[(size_t)(m * 25 + j0 + g) * 256 + c] = (bf16_t)s[g][nt];
      }
  }
}

// -------- fused: h += ssp(agg @ lin2 + b); optionally hl = h @ lin1 --------
// 32 nodes/block (grid 157): halves weight refetch vs 16-node version
__global__ __launch_bounds__(256) void k_updlin(
    const bf16_t* __restrict__ agg, const bf16_t* __restrict__ lin2T,
    const float* __restrict__ lin2b, bf16_t* h16,
    const bf16_t* __restrict__ lin1T, bf16_t* __restrict__ hl, int do_lin1) {
  __shared__ bf16_t buf[32 * 256];
  __shared__ bf16_t hbuf[32 * 256];
  const int tid = threadIdx.x, lane = tid & 63, wave = tid >> 6;
  const int l15 = lane & 15, quad = lane >> 4;
  const int row0 = blockIdx.x * 32;
  // async-stage agg + h rows (pad rows clamp to node NN-1; outputs guarded)
  for (int it = wave; it < 16; it += 4) {
    int C = it * 64 + lane;
    int r = C >> 5, kcs = C & 31;
    int node = row0 + r;
    size_t rowoff = (size_t)(node < NN ? node : NN - 1) * 256 + ((kcs ^ (r & 7)) << 3);
    async16(buf + it * 512, agg + rowoff);
    async16(hbuf + it * 512, h16 + rowoff);
  }
  __syncthreads();
  f32x4 acc[2][4];
  zacc(acc);
  gemm_lds<2, 4, 8>(buf, lin2T, 256, wave * 64, acc, lane);
  {
    float b2[4];
#pragma unroll
    for (int nt = 0; nt < 4; ++nt) b2[nt] = lin2b[wave * 64 + nt * 16 + l15];
#pragma unroll
    for (int rt = 0; rt < 2; ++rt)
#pragma unroll
      for (int reg = 0; reg < 4; ++reg) {
        int r = rt * 16 + quad * 4 + reg, node = row0 + r;
#pragma unroll
        for (int nt = 0; nt < 4; ++nt) {
          int c = wave * 64 + nt * 16 + l15;
          int idx = swz(r, c);
          float hn = (float)hbuf[idx] + ssp_f(acc[rt][nt][reg] + b2[nt]);
          bf16_t hb = (bf16_t)hn;
          hbuf[idx] = hb;
          if (node < NN) h16[(size_t)node * 256 + c] = hb;
        }
      }
  }
  if (!do_lin1) return;
  __syncthreads();
  f32x4 acc2[2][4];
  zacc(acc2);
  gemm_lds<2, 4, 8>(hbuf, lin1T, 256, wave * 64, acc2, lane);
#pragma unroll
  for (int rt = 0; rt < 2; ++rt)
#pragma unroll
    for (int reg = 0; reg < 4; ++reg) {
      int r = rt * 16 + quad * 4 + reg, node = row0 + r;
      if (node < NN) {
#pragma unroll
        for (int nt = 0; nt < 4; ++nt) {
          int c = wave * 64 + nt * 16 + l15;
          hl[(size_t)node * 256 + c] = (bf16_t)acc2[rt][nt][reg];
        }
      }
    }
}

// ---------------- hl = h @ lin1 (no bias), initial ----------------
__global__ __launch_bounds__(256) void k_lin1(
    const bf16_t* __restrict__ h16, const bf16_t* __restrict__ lin1T,
    bf16_t* __restrict__ hl) {
  __shared__ bf16_t buf[32 * 256];
  const int tid = threadIdx.x, lane = tid & 63, wave = tid >> 6;
  const int l15 = lane & 15, quad = lane >> 4;
  const int row0 = blockIdx.x * 32;
  for (int it = wave; it < 16; it += 4) {
    int C = it * 64 + lane;
    int r = C >> 5, kcs = C & 31;
    int node = row0 + r;
    async16(buf + it * 512,
            h16 + (size_t)(node < NN ? node : NN - 1) * 256 + ((kcs ^ (r & 7)) << 3));
  }
  __syncthreads();
  f32x4 acc[2][4];
  zacc(acc);
  gemm_lds<2, 4, 8>(buf, lin1T, 256, wave * 64, acc, lane);
#pragma unroll
  for (int rt = 0; rt < 2; ++rt)
#pragma unroll
    for (int reg = 0; reg < 4; ++reg) {
      int r = rt * 16 + quad * 4 + reg, node = row0 + r;
      if (node < NN) {
#pragma unroll
        for (int nt = 0; nt < 4; ++nt) {
          int c = wave * 64 + nt * 16 + l15;
          hl[(size_t)node * 256 + c] = (bf16_t)acc[rt][nt][reg];
        }
      }
    }
}

// ------- output head: dual-buffer, eattr async under GEMM1a -------
__global__ __launch_bounds__(512, 4) void k_head(
    const bf16_t* __restrict__ h16, const bf16_t* __restrict__ eattr, const int* ei,
    const float* gb1, const float* gb2, const float* gW3, const float* gb3,
    const bf16_t* WT, float* out) {
  __shared__ bf16_t B0[64 * 256];      // h_src * h_dst  (K 0-255)
  __shared__ bf16_t B1[64 * 256];      // eattr          (K 256-511)
  __shared__ int sP[64];
  const int tid = threadIdx.x, lane = tid & 63, wave = tid >> 6;
  const int l15 = lane & 15, quad = lane >> 4;
  const int eBase = blockIdx.x * 64;
  const int colB = wave * 32;

  if (tid < 64) sP[tid] = eperm(eBase + tid);
  for (int task = tid; task < 64 * 32; task += 512) {
    int r = task >> 5, kc = task & 31;
    int e = eBase + r, s = ei[e], dn = ei[EE + e];
    bf16x8 a = *(const bf16x8*)(h16 + (size_t)s * 256 + kc * 8);
    bf16x8 b = *(const bf16x8*)(h16 + (size_t)dn * 256 + kc * 8);
    bf16x8 v;
#pragma unroll
    for (int q = 0; q < 8; ++q) v[q] = (bf16_t)((float)a[q] * (float)b[q]);
    *(bf16x8*)(B0 + r * 256 + ((kc ^ (r & 7)) << 3)) = v;
  }
  __syncthreads();
  // issue eattr async-stage into B1 NOW; GEMM1a's 128 MFMA hide the latency,
  // and the next barrier's vmcnt drain guarantees completion before G1b.
  for (int it = wave; it < 32; it += 8) {
    int C = it * 64 + lane;
    int r = C >> 5, kcs = C & 31;
    async16(B1 + it * 512,
            eattr + (size_t)sP[r] * 256 + ((kcs ^ (r & 7)) << 3));
  }
  f32x4 acc1[4][2];
  zacc(acc1);
  gemm_lds<4, 2, 8>(B0, WT + OFF_GW1T, 256, colB, acc1, lane);
  __syncthreads();
  // gW1 K-rows 256..511 = fragment rows kc 32..63 -> base offset 32*256*8 = 65536
  gemm_lds<4, 2, 8>(B1, WT + OFF_GW1T + 65536, 256, colB, acc1, lane);
  // no barrier: epilogue writes B0 only; G1b reads B1 only.
  {
    float b1v[2];
#pragma unroll
    for (int nt = 0; nt < 2; ++nt) b1v[nt] = gb1[colB + nt * 16 + l15];
#pragma unroll
    for (int rt = 0; rt < 4; ++rt)
#pragma unroll
      for (int reg = 0; reg < 4; ++reg) {
        int r = rt * 16 + quad * 4 + reg;
#pragma unroll
        for (int nt = 0; nt < 2; ++nt) {
          int c = colB + nt * 16 + l15;
          B0[swz(r, c)] = (bf16_t)silu_f(acc1[rt][nt][reg] + b1v[nt]);
        }
      }
  }
  __syncthreads();
  f32x4 acc2[4][1];
  zacc(acc2);
  gemm_lds<4, 1, 8>(B0, WT + OFF_GW2T, 128, wave * 16, acc2, lane);
  __syncthreads();
  {
    float b2v = gb2[wave * 16 + l15];
#pragma unroll
    for (int rt = 0; rt < 4; ++rt)
#pragma unroll
      for (int reg = 0; reg < 4; ++reg) {
        int r = rt * 16 + quad * 4 + reg;
        int c = wave * 16 + l15;
        B0[swz(r, c)] = (bf16_t)silu_f(acc2[rt][0][reg] + b2v);
      }
  }
  __syncthreads();
  {
    // vectorized final dot over 128 cols: 2 x ds_read_b128 + 4 x f32x4 per thread
    int r = tid >> 3, part = tid & 7;
    float s = 0.f;
#pragma unroll
    for (int g = 0; g < 2; ++g) {
      int chunk = part * 2 + g;                       // col chunk (c = chunk*8+q)
      const bf16x8 v = *(const bf16x8*)(B0 + r * 256 + ((chunk ^ (r & 7)) << 3));
      const f32x4 w0 = *(const f32x4*)(gW3 + part * 16 + g * 8);
      const f32x4 w1 = *(const f32x4*)(gW3 + part * 16 + g * 8 + 4);
#pragma unroll
      for (int q = 0; q < 4; ++q) s += (float)v[q] * w0[q];
#pragma unroll
      for (int q = 0; q < 4; ++q) s += (float)v[4 + q] * w1[q];
    }
    s += __shfl_xor(s, 1);
    s += __shfl_xor(s, 2);
    s += __shfl_xor(s, 4);
    if (part == 0) out[eBase + r] = s + gb3[0];
  }
}

extern "C" void kernel_launch(void* const* d_in, const int* in_sizes, int n_in,
                              void* d_out, int out_size, void* d_ws, size_t ws_size,
                              hipStream_t stream) {
  const float* pos   = (const float*)d_in[0];
  const float* rfeat = (const float*)d_in[1];
  const float* pfeat = (const float*)d_in[2];
  const float* emb   = (const float*)d_in[3];
  const float* Wf    = (const float*)d_in[4];
  const float* bemb  = (const float*)d_in[5];
  const float* eeW1  = (const float*)d_in[6];
  const float* eeb1  = (const float*)d_in[7];
  const float* eeW2  = (const float*)d_in[8];
  const float* eeb2  = (const float*)d_in[9];
  const float* ecW1  = (const float*)d_in[10];
  const float* ecb1  = (const float*)d_in[11];
  const float* ecW2  = (const float*)d_in[12];
  const float* ecb2  = (const float*)d_in[13];
  const float* fW1   = (const float*)d_in[14];
  const float* fb1   = (const float*)d_in[15];
  const float* fW2   = (const float*)d_in[16];
  const float* fb2   = (const float*)d_in[17];
  const float* ln1   = (const float*)d_in[18];
  const float* ln2   = (const float*)d_in[19];
  const float* ln2b  = (const float*)d_in[20];
  const float* gW1   = (const float*)d_in[21];
  const float* gb1   = (const float*)d_in[22];
  const float* gW2   = (const float*)d_in[23];
  const float* gb2   = (const float*)d_in[24];
  const float* gW3   = (const float*)d_in[25];
  const float* gb3   = (const float*)d_in[26];
  const int* atype = (const int*)d_in[27];
  const int* ei    = (const int*)d_in[28];
  const int* etr   = (const int*)d_in[29];
  const int* etp   = (const int*)d_in[30];
  (void)etr; (void)etp;

  float* out = (float*)d_out;
  char* ws = (char*)d_ws;
  bf16_t* WT     = (bf16_t*)(ws);
  bf16_t* h16    = (bf16_t*)(ws + WSOFF_H16);
  bf16_t* hl     = (bf16_t*)(ws + WSOFF_HL);
  bf16_t* agg    = (bf16_t*)(ws + WSOFF_AGG);
  bf16_t* eattr  = (bf16_t*)(ws + WSOFF_EATTR);
  bf16_t* wfoldT = (bf16_t*)(ws + WSOFF_AGG);                  // transient, pre-conv
  float*  bfold  = (float*)(ws + WSOFF_AGG + AGGOFF_BFOLD);    // transient
  int*    perm   = (int*)(ws + WSOFF_AGG + AGGOFF_PERM);       // transient

  // fused setup: fold(x4-tiled, first) + foldb + repack + node + prep + out-copy
  k_setup<<<8691, 256, 0, stream>>>(eeW2, ecW1, ecW2, fW1, fW2, ln1, ln2, gW1, gW2, WT,
                                    bemb, eeb2, ecb1, wfoldT, bfold, perm,
                                    rfeat, pfeat, emb, Wf, atype, h16, ei, out);
  k_edge_attr<<<1876, 512, 0, stream>>>(pos, ei, eeW1, eeb1, ecb2,
                                        wfoldT, bfold, perm, WT, eattr, out);
  k_lin1<<<157, 256, 0, stream>>>(h16, WT + OFF_LN1T, hl);
  for (int l = 0; l < 4; ++l) {
    k_msg<<<1000, 512, 0, stream>>>(eattr, hl,
                                    WT + OFF_FW1T + l * 65536, WT + OFF_FW2T + l * 65536,
                                    fb1 + l * 256, fb2 + l * 256, agg);
    k_updlin<<<157, 256, 0, stream>>>(agg, WT + OFF_LN2T + l * 65536, ln2b + l * 256,
                                      h16, WT + OFF_LN1T + (l + 1 < 4 ? l + 1 : 0) * 65536,
                                      hl, l < 3 ? 1 : 0);
  }
  k_head<<<EE / 64, 512, 0, stream>>>(h16, eattr, ei, gb1, gb2, gW3, gb3, WT, out);
}